// Round 1
// baseline (1575.429 us; speedup 1.0000x reference)
//
#include <hip/hip_runtime.h>
#include <stdint.h>

#define NPIX   65536
#define NIMG   8
#define NCH    64
#define KSEL   2048
#define NFG    1024
#define NRING  768
#define NBG    256
#define INV_TEMP 14.285714285714286f   // 1/0.07

// ---------------- Threefry-2x32 (20 rounds), exactly as JAX's lowering ------
__device__ __forceinline__ void tf2x32(uint32_t k0, uint32_t k1,
                                       uint32_t& x0, uint32_t& x1) {
  const uint32_t ks2 = k0 ^ k1 ^ 0x1BD11BDAu;
  x0 += k0; x1 += k1;
#define TF_RND(r) { x0 += x1; x1 = (x1 << (r)) | (x1 >> (32 - (r))); x1 ^= x0; }
  TF_RND(13) TF_RND(15) TF_RND(26) TF_RND(6)
  x0 += k1;  x1 += ks2 + 1u;
  TF_RND(17) TF_RND(29) TF_RND(16) TF_RND(24)
  x0 += ks2; x1 += k0 + 2u;
  TF_RND(13) TF_RND(15) TF_RND(26) TF_RND(6)
  x0 += k0;  x1 += k1 + 3u;
  TF_RND(17) TF_RND(29) TF_RND(16) TF_RND(24)
  x0 += k1;  x1 += ks2 + 4u;
  TF_RND(13) TF_RND(15) TF_RND(26) TF_RND(6)
  x0 += ks2; x1 += k0 + 5u;
#undef TF_RND
}

// ---------------- keys: JAX partitionable split; also zero the output -------
// root = key(1) = (0,1). image key b = cipher(root,(0,b)).
// per-image subkeys g=0..2: cipher(key_b,(0,g)).
__global__ void compute_keys(uint32_t* __restrict__ keys, float* __restrict__ out) {
  if (threadIdx.x == 0 && blockIdx.x == 0) {
    out[0] = 0.0f;
    for (int b = 0; b < NIMG; ++b) {
      uint32_t kb0 = 0u, kb1 = (uint32_t)b;
      tf2x32(0u, 1u, kb0, kb1);
      for (int g = 0; g < 3; ++g) {
        uint32_t x0 = 0u, x1 = (uint32_t)g;
        tf2x32(kb0, kb1, x0, x1);
        keys[(b * 3 + g) * 2 + 0] = x0;
        keys[(b * 3 + g) * 2 + 1] = x1;
      }
    }
  }
}

// ---------------- masks: horizontal then vertical Chebyshev-10 dilation -----
__global__ __launch_bounds__(256) void dilate_h(const int* __restrict__ labels,
                                                uint8_t* __restrict__ hdil) {
  int p = blockIdx.x * 256 + threadIdx.x;          // 0 .. 8*65536-1
  int b = p >> 16, pix = p & 65535;
  int i = pix >> 8, j = pix & 255;
  const int* L = labels + (b << 16) + (i << 8);
  int lo = j - 10 > 0 ? j - 10 : 0;
  int hi = j + 10 < 255 ? j + 10 : 255;
  uint8_t v = 0;
  for (int jj = lo; jj <= hi; ++jj) v |= (L[jj] == 1);
  hdil[p] = v;
}

// group id: 0 = fg, 1 = ring (dilated & !fg), 2 = interior bg
__global__ __launch_bounds__(256) void dilate_v_group(const int* __restrict__ labels,
                                                      const uint8_t* __restrict__ hdil,
                                                      uint8_t* __restrict__ gmask) {
  int p = blockIdx.x * 256 + threadIdx.x;
  int b = p >> 16, pix = p & 65535;
  int i = pix >> 8, j = pix & 255;
  uint8_t grp;
  if (labels[p] == 1) {
    grp = 0;
  } else {
    int lo = i - 10 > 0 ? i - 10 : 0;
    int hi = i + 10 < 255 ? i + 10 : 255;
    uint8_t d = 0;
    for (int ii = lo; ii <= hi; ++ii) d |= hdil[(b << 16) + (ii << 8) + j];
    grp = d ? 1 : 2;
  }
  gmask[p] = grp;
}

// ---------------- exact top-k selection (radix-select on 23-bit mantissa) ---
// one block per (image, group). Order within a segment is irrelevant (the loss
// is permutation-invariant inside each label segment), but the SET must match
// jax.lax.top_k: value desc, tie -> lower index first.
__global__ __launch_bounds__(1024) void select_topk(const uint8_t* __restrict__ gmask,
                                                    const uint32_t* __restrict__ keys,
                                                    int* __restrict__ idx_out) {
  const int task = blockIdx.x;            // 24 = 8 images x 3 groups
  const int b = task / 3, grp = task % 3;
  const int nsel = (grp == 0) ? NFG : (grp == 1) ? NRING : NBG;
  const int seg  = (grp == 0) ? 0 : (grp == 1) ? NFG : (NFG + NRING);
  const uint32_t k0 = keys[task * 2], k1 = keys[task * 2 + 1];
  const uint8_t* g = gmask + b * NPIX;
  int* out = idx_out + b * KSEL + seg;

  __shared__ uint32_t hist[4096];
  __shared__ unsigned long long buf[4096];
  __shared__ uint32_t cnt_above, cnt_T, sT, sG;

  for (int i = threadIdx.x; i < 4096; i += blockDim.x) hist[i] = 0;
  if (threadIdx.x == 0) { cnt_above = 0; cnt_T = 0; }
  __syncthreads();

  // pass 1: histogram of top-12 bits of m = bits >> 9
  for (int p = threadIdx.x; p < NPIX; p += blockDim.x) {
    if (g[p] != grp) continue;
    uint32_t x0 = 0u, x1 = (uint32_t)p;
    tf2x32(k0, k1, x0, x1);
    uint32_t m = (x0 ^ x1) >> 9;
    atomicAdd(&hist[m >> 11], 1u);
  }
  __syncthreads();

  if (threadIdx.x == 0) {
    uint32_t cum = 0; int T = 4095;
    for (; T > 0; --T) {
      uint32_t c = hist[T];
      if (cum + c >= (uint32_t)nsel) break;
      cum += c;
    }
    sT = (uint32_t)T; sG = cum;      // cum = count strictly above bucket T
  }
  __syncthreads();
  const uint32_t T = sT, G = sG;

  // pass 2: emit all strictly-above; collect threshold-bucket candidates
  for (int p = threadIdx.x; p < NPIX; p += blockDim.x) {
    if (g[p] != grp) continue;
    uint32_t x0 = 0u, x1 = (uint32_t)p;
    tf2x32(k0, k1, x0, x1);
    uint32_t m = (x0 ^ x1) >> 9;
    uint32_t bk = m >> 11;
    if (bk > T) {
      out[atomicAdd(&cnt_above, 1u)] = p;
    } else if (bk == T) {
      uint32_t s = atomicAdd(&cnt_T, 1u);
      if (s < 4096u) buf[s] = ((unsigned long long)m << 32) | (uint32_t)p;
    }
  }
  __syncthreads();

  // pick top-r from the threshold bucket by (m desc, idx asc) via O(c^2) rank
  const int r = nsel - (int)G;
  const int c = (int)(cnt_T < 4096u ? cnt_T : 4096u);
  for (int i = threadIdx.x; i < c; i += blockDim.x) {
    unsigned long long me = buf[i];
    uint32_t mm = (uint32_t)(me >> 32), pi = (uint32_t)me;
    int rank = 0;
    for (int j = 0; j < c; ++j) {
      unsigned long long o = buf[j];
      uint32_t om = (uint32_t)(o >> 32), op = (uint32_t)o;
      if (om > mm || (om == mm && op < pi)) ++rank;
    }
    if (rank < r) out[(int)G + rank] = (int)pi;
  }
}

// ---------------- gather + L2 normalize: one wave per selected pixel --------
__global__ __launch_bounds__(256) void gather_norm(const float* __restrict__ feats,
                                                   const int* __restrict__ idx,
                                                   float* __restrict__ fs) {
  int gtid = blockIdx.x * 256 + threadIdx.x;
  int w = gtid >> 6;                 // anchor id 0..16383
  int lane = gtid & 63;              // channel
  int b = w >> 11;
  int pix = idx[w];
  float v = feats[(size_t)(b * NCH + lane) * NPIX + (size_t)pix];
  float ss = v * v;
  #pragma unroll
  for (int o = 32; o > 0; o >>= 1) ss += __shfl_xor(ss, o);
  float scale = 1.0f / fmaxf(sqrtf(ss), 1e-12f);
  fs[(size_t)w * NCH + lane] = v * scale;
}

// ---------------- contrastive loss over the 2048x2048 logit matrix ----------
// Row-max shift cancels in pos/denom ratio -> skipped (exp args bounded).
#define TA 16
__global__ __launch_bounds__(256) void loss_kernel(const float* __restrict__ fs,
                                                   float* __restrict__ out) {
  const int b = blockIdx.x >> 6;          // image
  const int a0 = (blockIdx.x & 63) * TA;  // anchor tile (rows 0..1023 are fg)
  const float* F = fs + (size_t)b * KSEL * NCH;

  __shared__ float4 A4[TA][16];
  __shared__ float accD[TA], accP[TA];
  for (int t = threadIdx.x; t < TA * 16; t += blockDim.x) {
    int a = t >> 4, c4 = t & 15;
    A4[a][c4] = ((const float4*)(F + (size_t)(a0 + a) * NCH))[c4];
  }
  if (threadIdx.x < TA) { accD[threadIdx.x] = 0.f; accP[threadIdx.x] = 0.f; }
  __syncthreads();

  float locD[TA], locP[TA];
  #pragma unroll
  for (int a = 0; a < TA; ++a) { locD[a] = 0.f; locP[a] = 0.f; }

  for (int j = threadIdx.x; j < KSEL; j += 256) {
    float4 Fj[16];
    const float4* src = (const float4*)(F + (size_t)j * NCH);
    #pragma unroll
    for (int c = 0; c < 16; ++c) Fj[c] = src[c];
    #pragma unroll
    for (int a = 0; a < TA; ++a) {
      if (j == a0 + a) continue;          // ~eye: skip diagonal
      float4 acc = {0.f, 0.f, 0.f, 0.f};
      #pragma unroll
      for (int c = 0; c < 16; ++c) {
        float4 x = A4[a][c];
        acc.x += x.x * Fj[c].x; acc.y += x.y * Fj[c].y;
        acc.z += x.z * Fj[c].z; acc.w += x.w * Fj[c].w;
      }
      float dot = (acc.x + acc.y) + (acc.z + acc.w);
      float e = __expf(dot * INV_TEMP);
      locD[a] += e;
      if (j < NFG) locP[a] += e;          // positives: fg columns
    }
  }
  #pragma unroll
  for (int a = 0; a < TA; ++a) {
    atomicAdd(&accD[a], locD[a]);
    atomicAdd(&accP[a], locP[a]);
  }
  __syncthreads();
  if (threadIdx.x < TA) {
    float d = fmaxf(accD[threadIdx.x], 1e-8f);
    float p = fmaxf(accP[threadIdx.x], 1e-8f);
    float term = __logf(d) - __logf(p);
    atomicAdd(out, term * (1.0f / (NFG * NIMG)));   // /1024 per image, /8 images
  }
}

// ---------------- launcher ---------------------------------------------------
extern "C" void kernel_launch(void* const* d_in, const int* in_sizes, int n_in,
                              void* d_out, int out_size, void* d_ws, size_t ws_size,
                              hipStream_t stream) {
  const float* feats = (const float*)d_in[0];
  const int* labels  = (const int*)d_in[1];
  float* out = (float*)d_out;

  char* ws = (char*)d_ws;
  uint8_t*  gmask = (uint8_t*)(ws);                    // 524288 B
  uint8_t*  hdil  = (uint8_t*)(ws + 524288);           // 524288 B
  uint32_t* keys  = (uint32_t*)(ws + 1048576);         // 192 B
  int*      idx   = (int*)(ws + 1048832);              // 65536 B
  float*    fs    = (float*)(ws + 1114368);            // 4 MB

  hipLaunchKernelGGL(compute_keys, dim3(1), dim3(64), 0, stream, keys, out);
  hipLaunchKernelGGL(dilate_h, dim3((NIMG * NPIX) / 256), dim3(256), 0, stream,
                     labels, hdil);
  hipLaunchKernelGGL(dilate_v_group, dim3((NIMG * NPIX) / 256), dim3(256), 0, stream,
                     labels, hdil, gmask);
  hipLaunchKernelGGL(select_topk, dim3(NIMG * 3), dim3(1024), 0, stream,
                     gmask, keys, idx);
  hipLaunchKernelGGL(gather_norm, dim3((NIMG * KSEL * 64) / 256), dim3(256), 0, stream,
                     feats, idx, fs);
  hipLaunchKernelGGL(loss_kernel, dim3(NIMG * (NFG / TA)), dim3(256), 0, stream,
                     fs, out);
}

// Round 2
// 369.570 us; speedup vs baseline: 4.2629x; 4.2629x over previous
//
#include <hip/hip_runtime.h>
#include <stdint.h>

#define NPIX   65536
#define NIMG   8
#define NCH    64
#define KSEL   2048
#define NFG    1024
#define NRING  768
#define NBG    256
#define INV_TEMP 14.285714285714286f   // 1/0.07

// ---------------- Threefry-2x32 (20 rounds), exactly as JAX's lowering ------
__device__ __forceinline__ void tf2x32(uint32_t k0, uint32_t k1,
                                       uint32_t& x0, uint32_t& x1) {
  const uint32_t ks2 = k0 ^ k1 ^ 0x1BD11BDAu;
  x0 += k0; x1 += k1;
#define TF_RND(r) { x0 += x1; x1 = (x1 << (r)) | (x1 >> (32 - (r))); x1 ^= x0; }
  TF_RND(13) TF_RND(15) TF_RND(26) TF_RND(6)
  x0 += k1;  x1 += ks2 + 1u;
  TF_RND(17) TF_RND(29) TF_RND(16) TF_RND(24)
  x0 += ks2; x1 += k0 + 2u;
  TF_RND(13) TF_RND(15) TF_RND(26) TF_RND(6)
  x0 += k0;  x1 += k1 + 3u;
  TF_RND(17) TF_RND(29) TF_RND(16) TF_RND(24)
  x0 += k1;  x1 += ks2 + 4u;
  TF_RND(13) TF_RND(15) TF_RND(26) TF_RND(6)
  x0 += ks2; x1 += k0 + 5u;
#undef TF_RND
}

// ---------------- keys (JAX partitionable split) + zero scalar output -------
__global__ void compute_keys(uint32_t* __restrict__ keys, float* __restrict__ out) {
  if (threadIdx.x == 0 && blockIdx.x == 0) {
    out[0] = 0.0f;
    for (int b = 0; b < NIMG; ++b) {
      uint32_t kb0 = 0u, kb1 = (uint32_t)b;
      tf2x32(0u, 1u, kb0, kb1);
      for (int g = 0; g < 3; ++g) {
        uint32_t x0 = 0u, x1 = (uint32_t)g;
        tf2x32(kb0, kb1, x0, x1);
        keys[(b * 3 + g) * 2 + 0] = x0;
        keys[(b * 3 + g) * 2 + 1] = x1;
      }
    }
  }
}

__global__ __launch_bounds__(256) void zero_acc(float* __restrict__ acc) {
  ((float4*)acc)[blockIdx.x * 256 + threadIdx.x] = make_float4(0.f, 0.f, 0.f, 0.f);
}

// ---------------- masks: separable Chebyshev-10 dilation --------------------
__global__ __launch_bounds__(256) void dilate_h(const int* __restrict__ labels,
                                                uint8_t* __restrict__ hdil) {
  int p = blockIdx.x * 256 + threadIdx.x;
  int b = p >> 16, pix = p & 65535;
  int i = pix >> 8, j = pix & 255;
  const int* L = labels + (b << 16) + (i << 8);
  int lo = j - 10 > 0 ? j - 10 : 0;
  int hi = j + 10 < 255 ? j + 10 : 255;
  uint8_t v = 0;
  for (int jj = lo; jj <= hi; ++jj) v |= (L[jj] == 1);
  hdil[p] = v;
}

// group id: 0 = fg, 1 = ring, 2 = interior bg
__global__ __launch_bounds__(256) void dilate_v_group(const int* __restrict__ labels,
                                                      const uint8_t* __restrict__ hdil,
                                                      uint8_t* __restrict__ gmask) {
  int p = blockIdx.x * 256 + threadIdx.x;
  int b = p >> 16, pix = p & 65535;
  int i = pix >> 8, j = pix & 255;
  uint8_t grp;
  if (labels[p] == 1) {
    grp = 0;
  } else {
    int lo = i - 10 > 0 ? i - 10 : 0;
    int hi = i + 10 < 255 ? i + 10 : 255;
    uint8_t d = 0;
    for (int ii = lo; ii <= hi; ++ii) d |= hdil[(b << 16) + (ii << 8) + j];
    grp = d ? 1 : 2;
  }
  gmask[p] = grp;
}

// ---------------- exact top-k selection (radix-select, ties -> low idx) -----
__global__ __launch_bounds__(1024) void select_topk(const uint8_t* __restrict__ gmask,
                                                    const uint32_t* __restrict__ keys,
                                                    int* __restrict__ idx_out) {
  const int task = blockIdx.x;            // 24 = 8 images x 3 groups
  const int b = task / 3, grp = task % 3;
  const int nsel = (grp == 0) ? NFG : (grp == 1) ? NRING : NBG;
  const int seg  = (grp == 0) ? 0 : (grp == 1) ? NFG : (NFG + NRING);
  const uint32_t k0 = keys[task * 2], k1 = keys[task * 2 + 1];
  const uint8_t* g = gmask + b * NPIX;
  int* out = idx_out + b * KSEL + seg;

  __shared__ uint32_t hist[4096];
  __shared__ unsigned long long buf[4096];
  __shared__ uint32_t cnt_above, cnt_T, sT, sG;

  for (int i = threadIdx.x; i < 4096; i += blockDim.x) hist[i] = 0;
  if (threadIdx.x == 0) { cnt_above = 0; cnt_T = 0; }
  __syncthreads();

  for (int p = threadIdx.x; p < NPIX; p += blockDim.x) {
    if (g[p] != grp) continue;
    uint32_t x0 = 0u, x1 = (uint32_t)p;
    tf2x32(k0, k1, x0, x1);
    uint32_t m = (x0 ^ x1) >> 9;
    atomicAdd(&hist[m >> 11], 1u);
  }
  __syncthreads();

  if (threadIdx.x == 0) {
    uint32_t cum = 0; int T = 4095;
    for (; T > 0; --T) {
      uint32_t c = hist[T];
      if (cum + c >= (uint32_t)nsel) break;
      cum += c;
    }
    sT = (uint32_t)T; sG = cum;
  }
  __syncthreads();
  const uint32_t T = sT, G = sG;

  for (int p = threadIdx.x; p < NPIX; p += blockDim.x) {
    if (g[p] != grp) continue;
    uint32_t x0 = 0u, x1 = (uint32_t)p;
    tf2x32(k0, k1, x0, x1);
    uint32_t m = (x0 ^ x1) >> 9;
    uint32_t bk = m >> 11;
    if (bk > T) {
      out[atomicAdd(&cnt_above, 1u)] = p;
    } else if (bk == T) {
      uint32_t s = atomicAdd(&cnt_T, 1u);
      if (s < 4096u) buf[s] = ((unsigned long long)m << 32) | (uint32_t)p;
    }
  }
  __syncthreads();

  const int r = nsel - (int)G;
  const int c = (int)(cnt_T < 4096u ? cnt_T : 4096u);
  for (int i = threadIdx.x; i < c; i += blockDim.x) {
    unsigned long long me = buf[i];
    uint32_t mm = (uint32_t)(me >> 32), pi = (uint32_t)me;
    int rank = 0;
    for (int j = 0; j < c; ++j) {
      unsigned long long o = buf[j];
      uint32_t om = (uint32_t)(o >> 32), op = (uint32_t)o;
      if (om > mm || (om == mm && op < pi)) ++rank;
    }
    if (rank < r) out[(int)G + rank] = (int)pi;
  }
}

// ---------------- gather + L2 normalize + transpose to fsT[img][c][j] -------
// block = 256 threads handles 64 anchors. Load phase: thread (a=tid&63,
// q=tid>>6) gathers 16 channels of anchor a (inherently scattered by pix).
// Write phase: lanes sweep anchors -> fsT stores are 256B-contiguous per wave.
__global__ __launch_bounds__(256) void gather_t(const float* __restrict__ feats,
                                                const int* __restrict__ idx,
                                                float* __restrict__ fsT) {
  __shared__ float tile[64 * 65];   // [a][c], stride 65 -> 2-way banks (free)
  __shared__ float ssb[4 * 64];
  const int tid = threadIdx.x;
  const int a = tid & 63, q = tid >> 6;
  const int w = blockIdx.x * 64 + a;          // global anchor id
  const int img = blockIdx.x >> 5;            // 32 blocks per image
  const int pix = idx[w];
  const float* fb = feats + ((size_t)img * NCH + q * 16) * NPIX + pix;
  float ss = 0.f;
  #pragma unroll
  for (int k = 0; k < 16; ++k) {
    float v = fb[(size_t)k * NPIX];
    tile[a * 65 + q * 16 + k] = v;
    ss += v * v;
  }
  ssb[q * 64 + a] = ss;
  __syncthreads();

  const int j = (blockIdx.x & 31) * 64 + a;   // j index within image
  float tot = ssb[a] + ssb[64 + a] + ssb[128 + a] + ssb[192 + a];
  float scale = 1.0f / fmaxf(sqrtf(tot), 1e-12f);
  float* dst = fsT + (size_t)img * NCH * KSEL;
  #pragma unroll
  for (int k = 0; k < 16; ++k) {
    int c = q * 16 + k;
    dst[(size_t)c * KSEL + j] = tile[a * 65 + c] * scale;
  }
}

// ---------------- main loss GEMM: 8 anchors x 2048 columns per block --------
#define LTA 8
__global__ __launch_bounds__(256) void loss_main(const float* __restrict__ fsT,
                                                 float* __restrict__ accD,
                                                 float* __restrict__ accP) {
  const int img = blockIdx.x & 7;             // XCD swizzle: image b -> XCD b
  const int a0 = (blockIdx.x >> 3) * LTA;     // anchor tile, 0..1016
  const float* F = fsT + (size_t)img * NCH * KSEL;
  const float4* F4 = (const float4*)F;
  const int tid = threadIdx.x;

  __shared__ float As[LTA * 64];              // broadcast reads -> no conflicts
  for (int t = tid; t < LTA * 64; t += 256) {
    int a = t & 7, c = t >> 3;
    As[a * 64 + c] = F[(size_t)c * KSEL + a0 + a];
  }
  __syncthreads();

  float acc[LTA][8];
  #pragma unroll
  for (int a = 0; a < LTA; ++a)
    #pragma unroll
    for (int jj = 0; jj < 8; ++jj) acc[a][jj] = 0.f;

  #pragma unroll 4
  for (int c = 0; c < 64; ++c) {
    float4 b0 = F4[c * 512 + tid];            // j = 4*tid + [0..3]
    float4 b1 = F4[c * 512 + 256 + tid];      // j = 1024 + 4*tid + [0..3]
    #pragma unroll
    for (int a = 0; a < LTA; ++a) {
      float av = As[a * 64 + c];
      acc[a][0] += av * b0.x; acc[a][1] += av * b0.y;
      acc[a][2] += av * b0.z; acc[a][3] += av * b0.w;
      acc[a][4] += av * b1.x; acc[a][5] += av * b1.y;
      acc[a][6] += av * b1.z; acc[a][7] += av * b1.w;
    }
  }

  // epilogue: exp, mask diagonal, pos (j<1024) and denom partials
  float pD[LTA], pP[LTA];
  const int jb = 4 * tid;                     // first j of group A (fg columns)
  #pragma unroll
  for (int a = 0; a < LTA; ++a) {
    const int ag = a0 + a;                    // anchor global row (< 1024: fg)
    float p = 0.f, d = 0.f;
    #pragma unroll
    for (int jj = 0; jj < 4; ++jj) {
      float e = __expf(acc[a][jj] * INV_TEMP);
      if (jb + jj == ag) e = 0.f;             // ~eye
      p += e;
    }
    #pragma unroll
    for (int jj = 0; jj < 4; ++jj) d += __expf(acc[a][4 + jj] * INV_TEMP);
    pD[a] = d + p;                            // denom: all j except diag
    pP[a] = p;                                // positives: fg columns
  }

  #pragma unroll
  for (int o = 32; o > 0; o >>= 1) {
    #pragma unroll
    for (int a = 0; a < LTA; ++a) {
      pD[a] += __shfl_xor(pD[a], o);
      pP[a] += __shfl_xor(pP[a], o);
    }
  }
  if ((tid & 63) == 0) {
    #pragma unroll
    for (int a = 0; a < LTA; ++a) {
      atomicAdd(&accD[img * NFG + a0 + a], pD[a]);
      atomicAdd(&accP[img * NFG + a0 + a], pP[a]);
    }
  }
}

// ---------------- final: loss = mean over fg anchors of log(d) - log(p) -----
__global__ __launch_bounds__(256) void loss_final(const float* __restrict__ accD,
                                                  const float* __restrict__ accP,
                                                  float* __restrict__ out) {
  int t = blockIdx.x * 256 + threadIdx.x;     // 0 .. 8191
  float d = fmaxf(accD[t], 1e-8f);
  float p = fmaxf(accP[t], 1e-8f);
  float term = __logf(d) - __logf(p);
  #pragma unroll
  for (int o = 32; o > 0; o >>= 1) term += __shfl_xor(term, o);
  if ((threadIdx.x & 63) == 0)
    atomicAdd(out, term * (1.0f / (NFG * NIMG)));
}

// ---------------- launcher ---------------------------------------------------
extern "C" void kernel_launch(void* const* d_in, const int* in_sizes, int n_in,
                              void* d_out, int out_size, void* d_ws, size_t ws_size,
                              hipStream_t stream) {
  const float* feats = (const float*)d_in[0];
  const int* labels  = (const int*)d_in[1];
  float* out = (float*)d_out;

  char* ws = (char*)d_ws;
  uint8_t*  gmask = (uint8_t*)(ws);                    // 512 KB
  uint8_t*  hdil  = (uint8_t*)(ws + 524288);           // 512 KB
  uint32_t* keys  = (uint32_t*)(ws + 1048576);         // 192 B
  int*      idx   = (int*)(ws + 1049088);              // 64 KB
  float*    fsT   = (float*)(ws + 1114624);            // 4 MB  [8][64][2048]
  float*    accD  = (float*)(ws + 5308928);            // 32 KB [8][1024]
  float*    accP  = (float*)(ws + 5341696);            // 32 KB
  // accD/accP adjacent: zero 16384 floats = 4096 float4

  hipLaunchKernelGGL(compute_keys, dim3(1), dim3(64), 0, stream, keys, out);
  hipLaunchKernelGGL(zero_acc, dim3(16), dim3(256), 0, stream, accD);
  hipLaunchKernelGGL(dilate_h, dim3((NIMG * NPIX) / 256), dim3(256), 0, stream,
                     labels, hdil);
  hipLaunchKernelGGL(dilate_v_group, dim3((NIMG * NPIX) / 256), dim3(256), 0, stream,
                     labels, hdil, gmask);
  hipLaunchKernelGGL(select_topk, dim3(NIMG * 3), dim3(1024), 0, stream,
                     gmask, keys, idx);
  hipLaunchKernelGGL(gather_t, dim3((NIMG * KSEL) / 64), dim3(256), 0, stream,
                     feats, idx, fsT);
  hipLaunchKernelGGL(loss_main, dim3(NIMG * (NFG / LTA)), dim3(256), 0, stream,
                     fsT, accD, accP);
  hipLaunchKernelGGL(loss_final, dim3(NIMG * NFG / 256), dim3(256), 0, stream,
                     accD, accP, out);
}

// Round 3
// 294.339 us; speedup vs baseline: 5.3524x; 1.2556x over previous
//
#include <hip/hip_runtime.h>
#include <stdint.h>

#define NPIX   65536
#define NIMG   8
#define NCH    64
#define KSEL   2048
#define NFG    1024
#define NRING  768
#define NBG    256
#define INV_TEMP 14.285714285714286f   // 1/0.07

// ---------------- Threefry-2x32 (20 rounds), exactly as JAX's lowering ------
__device__ __forceinline__ void tf2x32(uint32_t k0, uint32_t k1,
                                       uint32_t& x0, uint32_t& x1) {
  const uint32_t ks2 = k0 ^ k1 ^ 0x1BD11BDAu;
  x0 += k0; x1 += k1;
#define TF_RND(r) { x0 += x1; x1 = (x1 << (r)) | (x1 >> (32 - (r))); x1 ^= x0; }
  TF_RND(13) TF_RND(15) TF_RND(26) TF_RND(6)
  x0 += k1;  x1 += ks2 + 1u;
  TF_RND(17) TF_RND(29) TF_RND(16) TF_RND(24)
  x0 += ks2; x1 += k0 + 2u;
  TF_RND(13) TF_RND(15) TF_RND(26) TF_RND(6)
  x0 += k0;  x1 += k1 + 3u;
  TF_RND(17) TF_RND(29) TF_RND(16) TF_RND(24)
  x0 += k1;  x1 += ks2 + 4u;
  TF_RND(13) TF_RND(15) TF_RND(26) TF_RND(6)
  x0 += ks2; x1 += k0 + 5u;
#undef TF_RND
}

// ---------------- keys (JAX partitionable split) + zero scalar output -------
__global__ void compute_keys(uint32_t* __restrict__ keys, float* __restrict__ out) {
  if (threadIdx.x == 0 && blockIdx.x == 0) {
    out[0] = 0.0f;
    for (int b = 0; b < NIMG; ++b) {
      uint32_t kb0 = 0u, kb1 = (uint32_t)b;
      tf2x32(0u, 1u, kb0, kb1);
      for (int g = 0; g < 3; ++g) {
        uint32_t x0 = 0u, x1 = (uint32_t)g;
        tf2x32(kb0, kb1, x0, x1);
        keys[(b * 3 + g) * 2 + 0] = x0;
        keys[(b * 3 + g) * 2 + 1] = x1;
      }
    }
  }
}

// zero the hist/cnt/candcnt/accD/accP region (ws is poisoned 0xAA every call)
#define ZERO_F4 5648
__global__ __launch_bounds__(256) void zero_ws(float4* __restrict__ z) {
  int t = blockIdx.x * 256 + threadIdx.x;
  if (t < ZERO_F4) z[t] = make_float4(0.f, 0.f, 0.f, 0.f);
}

// ---------------- horizontal Chebyshev-10 dilation --------------------------
__global__ __launch_bounds__(256) void dilate_h(const int* __restrict__ labels,
                                                uint8_t* __restrict__ hdil) {
  int p = blockIdx.x * 256 + threadIdx.x;
  int b = p >> 16, pix = p & 65535;
  int i = pix >> 8, j = pix & 255;
  const int* L = labels + (b << 16) + (i << 8);
  int lo = j - 10 > 0 ? j - 10 : 0;
  int hi = j + 10 < 255 ? j + 10 : 255;
  uint8_t v = 0;
  for (int jj = lo; jj <= hi; ++jj) v |= (L[jj] == 1);
  hdil[p] = v;
}

// ---------------- vertical dilation + group + per-pixel hash + histogram ----
// Each pixel belongs to exactly one group -> hash ONCE with that group's key.
// mgrp[p] = (m << 2) | grp, m = 23-bit uniform mantissa bits.
__global__ __launch_bounds__(256) void group_hash(const int* __restrict__ labels,
                                                  const uint8_t* __restrict__ hdil,
                                                  const uint32_t* __restrict__ keys,
                                                  uint32_t* __restrict__ mgrp,
                                                  uint32_t* __restrict__ hist) {
  __shared__ uint32_t lh[768];
  const int tid = threadIdx.x;
  for (int t = tid; t < 768; t += 256) lh[t] = 0;
  const int b = blockIdx.x >> 5;              // 32 blocks per image
  const int base = blockIdx.x * 2048;         // global pixel base
  const uint32_t K00 = keys[b * 6 + 0], K01 = keys[b * 6 + 1];
  const uint32_t K10 = keys[b * 6 + 2], K11 = keys[b * 6 + 3];
  const uint32_t K20 = keys[b * 6 + 4], K21 = keys[b * 6 + 5];
  __syncthreads();

  #pragma unroll
  for (int k = 0; k < 8; ++k) {
    int p = base + k * 256 + tid;
    int pix = p & 65535;
    int i = pix >> 8, j = pix & 255;
    uint32_t grp;
    if (labels[p] == 1) {
      grp = 0;
    } else {
      int lo = i - 10 > 0 ? i - 10 : 0;
      int hi = i + 10 < 255 ? i + 10 : 255;
      uint8_t d = 0;
      for (int ii = lo; ii <= hi; ++ii) d |= hdil[(b << 16) + (ii << 8) + j];
      grp = d ? 1u : 2u;
    }
    uint32_t k0 = grp == 0 ? K00 : grp == 1 ? K10 : K20;
    uint32_t k1 = grp == 0 ? K01 : grp == 1 ? K11 : K21;
    uint32_t x0 = 0u, x1 = (uint32_t)pix;
    tf2x32(k0, k1, x0, x1);
    uint32_t m = (x0 ^ x1) >> 9;
    mgrp[p] = (m << 2) | grp;
    atomicAdd(&lh[grp * 256 + (m >> 15)], 1u);
  }
  __syncthreads();
  for (int t = tid; t < 768; t += 256)
    if (lh[t]) atomicAdd(&hist[b * 768 + t], lh[t]);
}

// ---------------- find threshold bucket per task ----------------------------
__global__ void topk_thresh(const uint32_t* __restrict__ hist,
                            uint32_t* __restrict__ TG) {
  int task = threadIdx.x;
  if (task >= 24) return;
  int grp = task % 3;
  uint32_t nsel = grp == 0 ? NFG : grp == 1 ? NRING : NBG;
  const uint32_t* h = hist + task * 256;
  uint32_t cum = 0; int T = 255;
  for (; T > 0; --T) {
    uint32_t c = h[T];
    if (cum + c >= nsel) break;
    cum += c;
  }
  TG[task * 2] = (uint32_t)T;
  TG[task * 2 + 1] = cum;            // count strictly above bucket T
}

// ---------------- emit above-threshold + collect boundary candidates --------
__global__ __launch_bounds__(256) void topk_emit(const uint32_t* __restrict__ mgrp,
                                                 const uint32_t* __restrict__ TG,
                                                 uint32_t* __restrict__ cnt,
                                                 uint32_t* __restrict__ candcnt,
                                                 unsigned long long* __restrict__ cand,
                                                 int* __restrict__ idx_out) {
  __shared__ uint32_t loc[3], lbd[3], basA[3], basB[3];
  const int tid = threadIdx.x;
  const int b = blockIdx.x >> 5;
  const int base = blockIdx.x * 2048;
  if (tid < 3) { loc[tid] = 0; lbd[tid] = 0; }
  __syncthreads();
  const uint32_t T0 = TG[(b * 3 + 0) * 2];
  const uint32_t T1 = TG[(b * 3 + 1) * 2];
  const uint32_t T2 = TG[(b * 3 + 2) * 2];

  #pragma unroll
  for (int k = 0; k < 8; ++k) {
    uint32_t v = mgrp[base + k * 256 + tid];
    uint32_t g = v & 3u, bin = v >> 17;
    uint32_t T = g == 0 ? T0 : g == 1 ? T1 : T2;
    if (bin > T) atomicAdd(&loc[g], 1u);
    else if (bin == T) atomicAdd(&lbd[g], 1u);
  }
  __syncthreads();
  if (tid < 3) {
    basA[tid] = atomicAdd(&cnt[b * 3 + tid], loc[tid]);
    basB[tid] = atomicAdd(&candcnt[b * 3 + tid], lbd[tid]);
    loc[tid] = 0; lbd[tid] = 0;
  }
  __syncthreads();

  #pragma unroll
  for (int k = 0; k < 8; ++k) {
    int p = base + k * 256 + tid;
    uint32_t v = mgrp[p];
    uint32_t g = v & 3u, bin = v >> 17;
    uint32_t T = g == 0 ? T0 : g == 1 ? T1 : T2;
    int pix = p & 65535;
    if (bin > T) {
      uint32_t o = atomicAdd(&loc[g], 1u);
      int seg = g == 0 ? 0 : g == 1 ? NFG : (NFG + NRING);
      idx_out[b * KSEL + seg + (int)(basA[g] + o)] = pix;
    } else if (bin == T) {
      uint32_t o = atomicAdd(&lbd[g], 1u);
      uint32_t c = basB[g] + o;
      uint32_t m = v >> 2;
      if (c < 1024u)
        cand[(b * 3 + g) * 1024 + c] = ((unsigned long long)m << 16) | (uint32_t)pix;
    }
  }
}

// ---------------- exact tie-break rank within the threshold bucket ----------
// order: m desc, pixel index asc (matches jax.lax.top_k stable ordering)
__global__ __launch_bounds__(256) void topk_rank(const uint32_t* __restrict__ TG,
                                                 const uint32_t* __restrict__ candcnt,
                                                 const unsigned long long* __restrict__ cand,
                                                 int* __restrict__ idx_out) {
  __shared__ unsigned long long cb[1024];
  const int task = blockIdx.x;
  const int b = task / 3, g = task % 3;
  const int nsel = g == 0 ? NFG : g == 1 ? NRING : NBG;
  const int seg  = g == 0 ? 0 : g == 1 ? NFG : (NFG + NRING);
  const uint32_t G = TG[task * 2 + 1];
  const int r = nsel - (int)G;
  const int c = (int)(candcnt[task] < 1024u ? candcnt[task] : 1024u);
  for (int i = threadIdx.x; i < c; i += 256) cb[i] = cand[task * 1024 + i];
  __syncthreads();
  for (int i = threadIdx.x; i < c; i += 256) {
    unsigned long long me = cb[i];
    uint32_t mm = (uint32_t)(me >> 16), pi = (uint32_t)(me & 0xFFFFu);
    int rank = 0;
    for (int j = 0; j < c; ++j) {
      unsigned long long o = cb[j];
      uint32_t om = (uint32_t)(o >> 16), op = (uint32_t)(o & 0xFFFFu);
      if (om > mm || (om == mm && op < pi)) ++rank;
    }
    if (rank < r) idx_out[b * KSEL + seg + (int)G + rank] = (int)pi;
  }
}

// ---------------- gather + L2 normalize + transpose to fsT[img][c][j] -------
__global__ __launch_bounds__(256) void gather_t(const float* __restrict__ feats,
                                                const int* __restrict__ idx,
                                                float* __restrict__ fsT) {
  __shared__ float tile[64 * 65];
  __shared__ float ssb[4 * 64];
  const int tid = threadIdx.x;
  const int a = tid & 63, q = tid >> 6;
  const int w = blockIdx.x * 64 + a;
  const int img = blockIdx.x >> 5;
  const int pix = idx[w];
  const float* fb = feats + ((size_t)img * NCH + q * 16) * NPIX + pix;
  float ss = 0.f;
  #pragma unroll
  for (int k = 0; k < 16; ++k) {
    float v = fb[(size_t)k * NPIX];
    tile[a * 65 + q * 16 + k] = v;
    ss += v * v;
  }
  ssb[q * 64 + a] = ss;
  __syncthreads();

  const int j = (blockIdx.x & 31) * 64 + a;
  float tot = ssb[a] + ssb[64 + a] + ssb[128 + a] + ssb[192 + a];
  float scale = 1.0f / fmaxf(sqrtf(tot), 1e-12f);
  float* dst = fsT + (size_t)img * NCH * KSEL;
  #pragma unroll
  for (int k = 0; k < 16; ++k) {
    int c = q * 16 + k;
    dst[(size_t)c * KSEL + j] = tile[a * 65 + c] * scale;
  }
}

// ---------------- main loss GEMM: 8 anchors x 2048 columns per block --------
#define LTA 8
__global__ __launch_bounds__(256) void loss_main(const float* __restrict__ fsT,
                                                 float* __restrict__ accD,
                                                 float* __restrict__ accP) {
  const int img = blockIdx.x & 7;             // XCD swizzle
  const int a0 = (blockIdx.x >> 3) * LTA;
  const float* F = fsT + (size_t)img * NCH * KSEL;
  const float4* F4 = (const float4*)F;
  const int tid = threadIdx.x;

  __shared__ float As[LTA * 64];
  for (int t = tid; t < LTA * 64; t += 256) {
    int a = t & 7, c = t >> 3;
    As[a * 64 + c] = F[(size_t)c * KSEL + a0 + a];
  }
  __syncthreads();

  float acc[LTA][8];
  #pragma unroll
  for (int a = 0; a < LTA; ++a)
    #pragma unroll
    for (int jj = 0; jj < 8; ++jj) acc[a][jj] = 0.f;

  #pragma unroll 4
  for (int c = 0; c < 64; ++c) {
    float4 b0 = F4[c * 512 + tid];
    float4 b1 = F4[c * 512 + 256 + tid];
    #pragma unroll
    for (int a = 0; a < LTA; ++a) {
      float av = As[a * 64 + c];
      acc[a][0] += av * b0.x; acc[a][1] += av * b0.y;
      acc[a][2] += av * b0.z; acc[a][3] += av * b0.w;
      acc[a][4] += av * b1.x; acc[a][5] += av * b1.y;
      acc[a][6] += av * b1.z; acc[a][7] += av * b1.w;
    }
  }

  float pD[LTA], pP[LTA];
  const int jb = 4 * tid;
  #pragma unroll
  for (int a = 0; a < LTA; ++a) {
    const int ag = a0 + a;
    float p = 0.f, d = 0.f;
    #pragma unroll
    for (int jj = 0; jj < 4; ++jj) {
      float e = __expf(acc[a][jj] * INV_TEMP);
      if (jb + jj == ag) e = 0.f;
      p += e;
    }
    #pragma unroll
    for (int jj = 0; jj < 4; ++jj) d += __expf(acc[a][4 + jj] * INV_TEMP);
    pD[a] = d + p;
    pP[a] = p;
  }

  #pragma unroll
  for (int o = 32; o > 0; o >>= 1) {
    #pragma unroll
    for (int a = 0; a < LTA; ++a) {
      pD[a] += __shfl_xor(pD[a], o);
      pP[a] += __shfl_xor(pP[a], o);
    }
  }
  if ((tid & 63) == 0) {
    #pragma unroll
    for (int a = 0; a < LTA; ++a) {
      atomicAdd(&accD[img * NFG + a0 + a], pD[a]);
      atomicAdd(&accP[img * NFG + a0 + a], pP[a]);
    }
  }
}

// ---------------- final: loss = mean over fg anchors of log(d) - log(p) -----
__global__ __launch_bounds__(256) void loss_final(const float* __restrict__ accD,
                                                  const float* __restrict__ accP,
                                                  float* __restrict__ out) {
  int t = blockIdx.x * 256 + threadIdx.x;
  float d = fmaxf(accD[t], 1e-8f);
  float p = fmaxf(accP[t], 1e-8f);
  float term = __logf(d) - __logf(p);
  #pragma unroll
  for (int o = 32; o > 0; o >>= 1) term += __shfl_xor(term, o);
  if ((threadIdx.x & 63) == 0)
    atomicAdd(out, term * (1.0f / (NFG * NIMG)));
}

// ---------------- launcher ---------------------------------------------------
extern "C" void kernel_launch(void* const* d_in, const int* in_sizes, int n_in,
                              void* d_out, int out_size, void* d_ws, size_t ws_size,
                              hipStream_t stream) {
  const float* feats = (const float*)d_in[0];
  const int* labels  = (const int*)d_in[1];
  float* out = (float*)d_out;

  char* ws = (char*)d_ws;
  uint8_t*  hdil    = (uint8_t*)(ws);                       // 512 KB
  uint32_t* mgrp    = (uint32_t*)(ws + 524288);             // 2 MB
  uint32_t* keys    = (uint32_t*)(ws + 2621440);            // 192 B
  uint32_t* TG      = (uint32_t*)(ws + 2621632);            // 192 B (24x2 u32)
  // --- contiguous zero region @2621824: hist,cnt,candcnt,accD,accP ---------
  uint32_t* hist    = (uint32_t*)(ws + 2621824);            // 24576 B
  uint32_t* cnt     = (uint32_t*)(ws + 2646400);            // 128 B
  uint32_t* candcnt = (uint32_t*)(ws + 2646528);            // 128 B
  float*    accD    = (float*)(ws + 2646656);               // 32 KB
  float*    accP    = (float*)(ws + 2679424);               // 32 KB  (ends 2712192)
  // ------------------------------------------------------------------------
  unsigned long long* cand = (unsigned long long*)(ws + 2712192); // 192 KB
  int*      idx     = (int*)(ws + 2908800);                 // 64 KB
  float*    fsT     = (float*)(ws + 2974336);               // 4 MB

  hipLaunchKernelGGL(compute_keys, dim3(1), dim3(64), 0, stream, keys, out);
  hipLaunchKernelGGL(zero_ws, dim3((ZERO_F4 + 255) / 256), dim3(256), 0, stream,
                     (float4*)hist);
  hipLaunchKernelGGL(dilate_h, dim3((NIMG * NPIX) / 256), dim3(256), 0, stream,
                     labels, hdil);
  hipLaunchKernelGGL(group_hash, dim3(NIMG * 32), dim3(256), 0, stream,
                     labels, hdil, keys, mgrp, hist);
  hipLaunchKernelGGL(topk_thresh, dim3(1), dim3(64), 0, stream, hist, TG);
  hipLaunchKernelGGL(topk_emit, dim3(NIMG * 32), dim3(256), 0, stream,
                     mgrp, TG, cnt, candcnt, cand, idx);
  hipLaunchKernelGGL(topk_rank, dim3(24), dim3(256), 0, stream,
                     TG, candcnt, cand, idx);
  hipLaunchKernelGGL(gather_t, dim3((NIMG * KSEL) / 64), dim3(256), 0, stream,
                     feats, idx, fsT);
  hipLaunchKernelGGL(loss_main, dim3(NIMG * (NFG / LTA)), dim3(256), 0, stream,
                     fsT, accD, accP);
  hipLaunchKernelGGL(loss_final, dim3(NIMG * NFG / 256), dim3(256), 0, stream,
                     accD, accP, out);
}

// Round 4
// 278.078 us; speedup vs baseline: 5.6654x; 1.0585x over previous
//
#include <hip/hip_runtime.h>
#include <stdint.h>

#define NPIX   65536
#define NIMG   8
#define NCH    64
#define KSEL   2048
#define NFG    1024
#define NRING  768
#define NBG    256
#define INV_TEMP 14.285714285714286f   // 1/0.07

// ---------------- Threefry-2x32 (20 rounds), exactly as JAX's lowering ------
__device__ __forceinline__ void tf2x32(uint32_t k0, uint32_t k1,
                                       uint32_t& x0, uint32_t& x1) {
  const uint32_t ks2 = k0 ^ k1 ^ 0x1BD11BDAu;
  x0 += k0; x1 += k1;
#define TF_RND(r) { x0 += x1; x1 = (x1 << (r)) | (x1 >> (32 - (r))); x1 ^= x0; }
  TF_RND(13) TF_RND(15) TF_RND(26) TF_RND(6)
  x0 += k1;  x1 += ks2 + 1u;
  TF_RND(17) TF_RND(29) TF_RND(16) TF_RND(24)
  x0 += ks2; x1 += k0 + 2u;
  TF_RND(13) TF_RND(15) TF_RND(26) TF_RND(6)
  x0 += k0;  x1 += k1 + 3u;
  TF_RND(17) TF_RND(29) TF_RND(16) TF_RND(24)
  x0 += k1;  x1 += ks2 + 4u;
  TF_RND(13) TF_RND(15) TF_RND(26) TF_RND(6)
  x0 += ks2; x1 += k0 + 5u;
#undef TF_RND
}

// ---------------- kernel 1: row dilation + side duties ----------------------
// 2048 blocks = 8 images x 256 rows; one block = one full row (j = 0..255).
// Side duties: blocks 0..6 zero the hist/cnt/candcnt region (poisoned 0xAA
// each call); block 7 thread 0 computes the 24 threefry subkeys + zeroes out.
#define ZERO_F4 1552
__global__ __launch_bounds__(256) void dilate_h(const int* __restrict__ labels,
                                                uint8_t* __restrict__ hdil,
                                                float4* __restrict__ zregion,
                                                uint32_t* __restrict__ keys,
                                                float* __restrict__ out) {
  __shared__ int row[256];
  const int p = blockIdx.x * 256 + threadIdx.x;
  row[threadIdx.x] = labels[p];

  if (blockIdx.x < 7) {
    int t = blockIdx.x * 256 + threadIdx.x;
    if (t < ZERO_F4) zregion[t] = make_float4(0.f, 0.f, 0.f, 0.f);
  } else if (blockIdx.x == 7 && threadIdx.x == 0) {
    out[0] = 0.0f;
    for (int b = 0; b < NIMG; ++b) {
      uint32_t kb0 = 0u, kb1 = (uint32_t)b;
      tf2x32(0u, 1u, kb0, kb1);   // JAX partitionable split: key(1) -> fold b
      for (int g = 0; g < 3; ++g) {
        uint32_t x0 = 0u, x1 = (uint32_t)g;
        tf2x32(kb0, kb1, x0, x1);
        keys[(b * 3 + g) * 2 + 0] = x0;
        keys[(b * 3 + g) * 2 + 1] = x1;
      }
    }
  }
  __syncthreads();

  const int j = threadIdx.x;
  int lo = j - 10 > 0 ? j - 10 : 0;
  int hi = j + 10 < 255 ? j + 10 : 255;
  uint8_t v = 0;
  for (int jj = lo; jj <= hi; ++jj) v |= (row[jj] == 1);
  hdil[p] = v;
}

// ---------------- kernel 2: vertical dilation + group + hash + histogram ----
// Each pixel belongs to exactly one group -> hash ONCE with that group's key.
// mgrp[p] = (m << 2) | grp, m = 23-bit uniform mantissa bits.
__global__ __launch_bounds__(256) void group_hash(const int* __restrict__ labels,
                                                  const uint8_t* __restrict__ hdil,
                                                  const uint32_t* __restrict__ keys,
                                                  uint32_t* __restrict__ mgrp,
                                                  uint32_t* __restrict__ hist) {
  __shared__ uint32_t lh[768];
  const int tid = threadIdx.x;
  for (int t = tid; t < 768; t += 256) lh[t] = 0;
  const int b = blockIdx.x >> 5;              // 32 blocks per image
  const int base = blockIdx.x * 2048;
  const uint32_t K00 = keys[b * 6 + 0], K01 = keys[b * 6 + 1];
  const uint32_t K10 = keys[b * 6 + 2], K11 = keys[b * 6 + 3];
  const uint32_t K20 = keys[b * 6 + 4], K21 = keys[b * 6 + 5];
  __syncthreads();

  #pragma unroll
  for (int k = 0; k < 8; ++k) {
    int p = base + k * 256 + tid;
    int pix = p & 65535;
    int i = pix >> 8, j = pix & 255;
    uint32_t grp;
    if (labels[p] == 1) {
      grp = 0;
    } else {
      int lo = i - 10 > 0 ? i - 10 : 0;
      int hi = i + 10 < 255 ? i + 10 : 255;
      uint8_t d = 0;
      for (int ii = lo; ii <= hi; ++ii) d |= hdil[(b << 16) + (ii << 8) + j];
      grp = d ? 1u : 2u;
    }
    uint32_t k0 = grp == 0 ? K00 : grp == 1 ? K10 : K20;
    uint32_t k1 = grp == 0 ? K01 : grp == 1 ? K11 : K21;
    uint32_t x0 = 0u, x1 = (uint32_t)pix;
    tf2x32(k0, k1, x0, x1);
    uint32_t m = (x0 ^ x1) >> 9;
    mgrp[p] = (m << 2) | grp;
    atomicAdd(&lh[grp * 256 + (m >> 15)], 1u);
  }
  __syncthreads();
  for (int t = tid; t < 768; t += 256)
    if (lh[t]) atomicAdd(&hist[b * 768 + t], lh[t]);
}

// ---------------- kernel 3: thresholds (inline) + emit ----------------------
// Every block redundantly computes its image's 3 thresholds from the global
// histogram (LDS-cached scan, deterministic => identical across blocks).
// Block (b*32) also publishes TG for the rank kernel.
__global__ __launch_bounds__(256) void topk_emit(const uint32_t* __restrict__ mgrp,
                                                 const uint32_t* __restrict__ hist,
                                                 uint32_t* __restrict__ TG,
                                                 uint32_t* __restrict__ cnt,
                                                 uint32_t* __restrict__ candcnt,
                                                 unsigned long long* __restrict__ cand,
                                                 int* __restrict__ idx_out) {
  __shared__ uint32_t hh[768];
  __shared__ uint32_t sT[3], loc[3], lbd[3], basA[3], basB[3];
  const int tid = threadIdx.x;
  const int b = blockIdx.x >> 5;
  const int base = blockIdx.x * 2048;
  for (int t = tid; t < 768; t += 256) hh[t] = hist[b * 768 + t];
  if (tid < 3) { loc[tid] = 0; lbd[tid] = 0; }
  __syncthreads();

  if (tid < 3) {
    uint32_t nsel = tid == 0 ? NFG : tid == 1 ? NRING : NBG;
    const uint32_t* h = hh + tid * 256;
    uint32_t cum = 0; int T = 255;
    for (; T > 0; --T) {
      uint32_t c = h[T];
      if (cum + c >= nsel) break;
      cum += c;
    }
    sT[tid] = (uint32_t)T;
    if ((blockIdx.x & 31) == 0) {
      TG[(b * 3 + tid) * 2] = (uint32_t)T;
      TG[(b * 3 + tid) * 2 + 1] = cum;      // count strictly above bucket T
    }
  }
  __syncthreads();
  const uint32_t T0 = sT[0], T1 = sT[1], T2 = sT[2];

  #pragma unroll
  for (int k = 0; k < 8; ++k) {
    uint32_t v = mgrp[base + k * 256 + tid];
    uint32_t g = v & 3u, bin = v >> 17;
    uint32_t T = g == 0 ? T0 : g == 1 ? T1 : T2;
    if (bin > T) atomicAdd(&loc[g], 1u);
    else if (bin == T) atomicAdd(&lbd[g], 1u);
  }
  __syncthreads();
  if (tid < 3) {
    basA[tid] = atomicAdd(&cnt[b * 3 + tid], loc[tid]);
    basB[tid] = atomicAdd(&candcnt[b * 3 + tid], lbd[tid]);
    loc[tid] = 0; lbd[tid] = 0;
  }
  __syncthreads();

  #pragma unroll
  for (int k = 0; k < 8; ++k) {
    int p = base + k * 256 + tid;
    uint32_t v = mgrp[p];
    uint32_t g = v & 3u, bin = v >> 17;
    uint32_t T = g == 0 ? T0 : g == 1 ? T1 : T2;
    int pix = p & 65535;
    if (bin > T) {
      uint32_t o = atomicAdd(&loc[g], 1u);
      int seg = g == 0 ? 0 : g == 1 ? NFG : (NFG + NRING);
      idx_out[b * KSEL + seg + (int)(basA[g] + o)] = pix;
    } else if (bin == T) {
      uint32_t o = atomicAdd(&lbd[g], 1u);
      uint32_t c = basB[g] + o;
      uint32_t m = v >> 2;
      if (c < 1024u)
        cand[(b * 3 + g) * 1024 + c] = ((unsigned long long)m << 16) | (uint32_t)pix;
    }
  }
}

// ---------------- kernel 4: exact tie-break rank in the threshold bucket ----
// order: m desc, pixel index asc (matches jax.lax.top_k stable ordering)
__global__ __launch_bounds__(256) void topk_rank(const uint32_t* __restrict__ TG,
                                                 const uint32_t* __restrict__ candcnt,
                                                 const unsigned long long* __restrict__ cand,
                                                 int* __restrict__ idx_out) {
  __shared__ unsigned long long cb[1024];
  const int task = blockIdx.x;
  const int b = task / 3, g = task % 3;
  const int nsel = g == 0 ? NFG : g == 1 ? NRING : NBG;
  const int seg  = g == 0 ? 0 : g == 1 ? NFG : (NFG + NRING);
  const uint32_t G = TG[task * 2 + 1];
  const int r = nsel - (int)G;
  const int c = (int)(candcnt[task] < 1024u ? candcnt[task] : 1024u);
  for (int i = threadIdx.x; i < c; i += 256) cb[i] = cand[task * 1024 + i];
  __syncthreads();
  for (int i = threadIdx.x; i < c; i += 256) {
    unsigned long long me = cb[i];
    uint32_t mm = (uint32_t)(me >> 16), pi = (uint32_t)(me & 0xFFFFu);
    int rank = 0;
    for (int j = 0; j < c; ++j) {
      unsigned long long o = cb[j];
      uint32_t om = (uint32_t)(o >> 16), op = (uint32_t)(o & 0xFFFFu);
      if (om > mm || (om == mm && op < pi)) ++rank;
    }
    if (rank < r) idx_out[b * KSEL + seg + (int)G + rank] = (int)pi;
  }
}

// ---------------- kernel 5: gather + L2 normalize + transpose ---------------
// 512 blocks x 256 thr = 8 waves/CU for the scattered HBM gather.
// thread (a = tid&31, q = tid>>5) loads channels q*8..q*8+7 of anchor a.
__global__ __launch_bounds__(256) void gather_t(const float* __restrict__ feats,
                                                const int* __restrict__ idx,
                                                float* __restrict__ fsT) {
  __shared__ float tile[32 * 65];   // [a][c], stride 65
  __shared__ float ssb[8 * 32];
  const int tid = threadIdx.x;
  const int a = tid & 31, q = tid >> 5;
  const int w = blockIdx.x * 32 + a;          // global anchor id
  const int img = blockIdx.x >> 6;            // 64 blocks per image
  const int pix = idx[w];
  const float* fb = feats + ((size_t)img * NCH + q * 8) * NPIX + pix;
  float ss = 0.f;
  #pragma unroll
  for (int k = 0; k < 8; ++k) {
    float v = fb[(size_t)k * NPIX];
    tile[a * 65 + q * 8 + k] = v;
    ss += v * v;
  }
  ssb[q * 32 + a] = ss;
  __syncthreads();

  const int a2 = tid & 31;
  const int j = (blockIdx.x & 63) * 32 + a2;  // j index within image
  float tot = 0.f;
  #pragma unroll
  for (int q2 = 0; q2 < 8; ++q2) tot += ssb[q2 * 32 + a2];
  float scale = 1.0f / fmaxf(sqrtf(tot), 1e-12f);
  float* dst = fsT + (size_t)img * NCH * KSEL;
  #pragma unroll
  for (int k = 0; k < 8; ++k) {
    int c = (tid >> 5) + 8 * k;
    dst[(size_t)c * KSEL + j] = tile[a2 * 65 + c] * scale;
  }
}

// ---------------- kernel 6: loss GEMM + per-anchor log + scalar reduce ------
// Each block owns 8 fg anchors x ALL 2048 columns -> complete D,P in-block,
// finish log(d)-log(p) here; one atomicAdd(out) per block (1024 total).
#define LTA 8
__global__ __launch_bounds__(256) void loss_main(const float* __restrict__ fsT,
                                                 float* __restrict__ out) {
  const int img = blockIdx.x & 7;             // XCD swizzle
  const int a0 = (blockIdx.x >> 3) * LTA;
  const float* F = fsT + (size_t)img * NCH * KSEL;
  const float4* F4 = (const float4*)F;
  const int tid = threadIdx.x;

  __shared__ float As[LTA * 64];
  __shared__ float redD[4][LTA], redP[4][LTA], terms[LTA];
  for (int t = tid; t < LTA * 64; t += 256) {
    int a = t & 7, c = t >> 3;
    As[a * 64 + c] = F[(size_t)c * KSEL + a0 + a];
  }
  __syncthreads();

  float acc[LTA][8];
  #pragma unroll
  for (int a = 0; a < LTA; ++a)
    #pragma unroll
    for (int jj = 0; jj < 8; ++jj) acc[a][jj] = 0.f;

  #pragma unroll 4
  for (int c = 0; c < 64; ++c) {
    float4 b0 = F4[c * 512 + tid];            // j = 4*tid + [0..3]  (fg cols)
    float4 b1 = F4[c * 512 + 256 + tid];      // j = 1024 + 4*tid + [0..3]
    #pragma unroll
    for (int a = 0; a < LTA; ++a) {
      float av = As[a * 64 + c];
      acc[a][0] += av * b0.x; acc[a][1] += av * b0.y;
      acc[a][2] += av * b0.z; acc[a][3] += av * b0.w;
      acc[a][4] += av * b1.x; acc[a][5] += av * b1.y;
      acc[a][6] += av * b1.z; acc[a][7] += av * b1.w;
    }
  }

  float pD[LTA], pP[LTA];
  const int jb = 4 * tid;
  #pragma unroll
  for (int a = 0; a < LTA; ++a) {
    const int ag = a0 + a;
    float p = 0.f, d = 0.f;
    #pragma unroll
    for (int jj = 0; jj < 4; ++jj) {
      float e = __expf(acc[a][jj] * INV_TEMP);
      if (jb + jj == ag) e = 0.f;             // ~eye
      p += e;
    }
    #pragma unroll
    for (int jj = 0; jj < 4; ++jj) d += __expf(acc[a][4 + jj] * INV_TEMP);
    pD[a] = d + p;
    pP[a] = p;
  }

  #pragma unroll
  for (int o = 32; o > 0; o >>= 1) {
    #pragma unroll
    for (int a = 0; a < LTA; ++a) {
      pD[a] += __shfl_xor(pD[a], o);
      pP[a] += __shfl_xor(pP[a], o);
    }
  }
  if ((tid & 63) == 0) {
    #pragma unroll
    for (int a = 0; a < LTA; ++a) {
      redD[tid >> 6][a] = pD[a];
      redP[tid >> 6][a] = pP[a];
    }
  }
  __syncthreads();
  if (tid < LTA) {
    float d = redD[0][tid] + redD[1][tid] + redD[2][tid] + redD[3][tid];
    float p = redP[0][tid] + redP[1][tid] + redP[2][tid] + redP[3][tid];
    d = fmaxf(d, 1e-8f); p = fmaxf(p, 1e-8f);
    terms[tid] = __logf(d) - __logf(p);
  }
  __syncthreads();
  if (tid == 0) {
    float s = 0.f;
    #pragma unroll
    for (int a = 0; a < LTA; ++a) s += terms[a];
    atomicAdd(out, s * (1.0f / (NFG * NIMG)));
  }
}

// ---------------- launcher ---------------------------------------------------
extern "C" void kernel_launch(void* const* d_in, const int* in_sizes, int n_in,
                              void* d_out, int out_size, void* d_ws, size_t ws_size,
                              hipStream_t stream) {
  const float* feats = (const float*)d_in[0];
  const int* labels  = (const int*)d_in[1];
  float* out = (float*)d_out;

  char* ws = (char*)d_ws;
  uint8_t*  hdil    = (uint8_t*)(ws);                       // 512 KB
  uint32_t* mgrp    = (uint32_t*)(ws + 524288);             // 2 MB
  uint32_t* keys    = (uint32_t*)(ws + 2621440);            // 256 B
  uint32_t* TG      = (uint32_t*)(ws + 2621696);            // 256 B
  // --- zero region @2621952: hist (24576) + cnt (128) + candcnt (128) -----
  uint32_t* hist    = (uint32_t*)(ws + 2621952);
  uint32_t* cnt     = (uint32_t*)(ws + 2646528);
  uint32_t* candcnt = (uint32_t*)(ws + 2646656);            // ends 2646784
  // ------------------------------------------------------------------------
  unsigned long long* cand = (unsigned long long*)(ws + 2646784); // 192 KB
  int*      idx     = (int*)(ws + 2843392);                 // 64 KB
  float*    fsT     = (float*)(ws + 2908928);               // 4 MB

  hipLaunchKernelGGL(dilate_h, dim3(NIMG * 256), dim3(256), 0, stream,
                     labels, hdil, (float4*)hist, keys, out);
  hipLaunchKernelGGL(group_hash, dim3(NIMG * 32), dim3(256), 0, stream,
                     labels, hdil, keys, mgrp, hist);
  hipLaunchKernelGGL(topk_emit, dim3(NIMG * 32), dim3(256), 0, stream,
                     mgrp, hist, TG, cnt, candcnt, cand, idx);
  hipLaunchKernelGGL(topk_rank, dim3(24), dim3(256), 0, stream,
                     TG, candcnt, cand, idx);
  hipLaunchKernelGGL(gather_t, dim3((NIMG * KSEL) / 32), dim3(256), 0, stream,
                     feats, idx, fsT);
  hipLaunchKernelGGL(loss_main, dim3(NIMG * (NFG / LTA)), dim3(256), 0, stream,
                     fsT, out);
}

// Round 5
// 250.371 us; speedup vs baseline: 6.2924x; 1.1107x over previous
//
#include <hip/hip_runtime.h>
#include <stdint.h>

#define NPIX   65536
#define NIMG   8
#define NCH    64
#define KSEL   2048
#define NFG    1024
#define NRING  768
#define NBG    256
#define INV_TEMP 14.285714285714286f   // 1/0.07

// ---------------- Threefry-2x32 (20 rounds), exactly as JAX's lowering ------
__device__ __forceinline__ void tf2x32(uint32_t k0, uint32_t k1,
                                       uint32_t& x0, uint32_t& x1) {
  const uint32_t ks2 = k0 ^ k1 ^ 0x1BD11BDAu;
  x0 += k0; x1 += k1;
#define TF_RND(r) { x0 += x1; x1 = (x1 << (r)) | (x1 >> (32 - (r))); x1 ^= x0; }
  TF_RND(13) TF_RND(15) TF_RND(26) TF_RND(6)
  x0 += k1;  x1 += ks2 + 1u;
  TF_RND(17) TF_RND(29) TF_RND(16) TF_RND(24)
  x0 += ks2; x1 += k0 + 2u;
  TF_RND(13) TF_RND(15) TF_RND(26) TF_RND(6)
  x0 += k0;  x1 += k1 + 3u;
  TF_RND(17) TF_RND(29) TF_RND(16) TF_RND(24)
  x0 += k1;  x1 += ks2 + 4u;
  TF_RND(13) TF_RND(15) TF_RND(26) TF_RND(6)
  x0 += ks2; x1 += k0 + 5u;
#undef TF_RND
}

// ---------------- kernel A: bit-packed separable dilation + side duties -----
// 32 blocks = 8 images x 4 row-bands of 64 rows (+10 halo each side).
// fg packed to 64-px u64 words via ballot; h-dilate by shifted ORs;
// v-dilate by 21 word-ORs. Side duties: block 0 zeroes hist/cnt/candcnt
// (ws poisoned 0xAA), block 1 computes threefry subkeys + zeroes out.
#define ZERO_F4 1552
__global__ __launch_bounds__(1024) void dilate_pack(const int* __restrict__ labels,
                                                    uint64_t* __restrict__ fgw,
                                                    uint64_t* __restrict__ dilw,
                                                    float4* __restrict__ zregion,
                                                    uint32_t* __restrict__ keys,
                                                    float* __restrict__ out) {
  __shared__ uint64_t fgs[336], hds[336];   // 84 rows x 4 words
  const int tid = threadIdx.x;
  const int img = blockIdx.x >> 2;
  const int r0 = (blockIdx.x & 3) * 64;

  if (blockIdx.x == 0) {
    for (int t = tid; t < ZERO_F4; t += 1024)
      zregion[t] = make_float4(0.f, 0.f, 0.f, 0.f);
  } else if (blockIdx.x == 1 && tid == 0) {
    out[0] = 0.0f;
    for (int b = 0; b < NIMG; ++b) {
      uint32_t kb0 = 0u, kb1 = (uint32_t)b;
      tf2x32(0u, 1u, kb0, kb1);   // JAX partitionable split: key(1) fold b
      for (int g = 0; g < 3; ++g) {
        uint32_t x0 = 0u, x1 = (uint32_t)g;
        tf2x32(kb0, kb1, x0, x1);
        keys[(b * 3 + g) * 2 + 0] = x0;
        keys[(b * 3 + g) * 2 + 1] = x1;
      }
    }
  }

  // pack fg bits for rows [r0-10, r0+74) (clamped rows contribute 0)
  #pragma unroll
  for (int it = 0; it < 21; ++it) {
    int li = it * 1024 + tid;                // 0 .. 21503 (84*256)
    int hr = r0 - 10 + (li >> 8);
    int col = li & 255;
    bool bit = false;
    if (hr >= 0 && hr < 256) bit = (labels[(img << 16) + (hr << 8) + col] == 1);
    uint64_t m = __ballot(bit);
    if ((tid & 63) == 0) fgs[li >> 6] = m;
  }
  __syncthreads();

  // horizontal dilation radius 10 within each row (4 words/row)
  for (int w = tid; w < 336; w += 1024) {
    int wc = w & 3;
    uint64_t x = fgs[w];
    uint64_t L = wc > 0 ? fgs[w - 1] : 0ull;
    uint64_t R = wc < 3 ? fgs[w + 1] : 0ull;
    uint64_t acc = x;
    #pragma unroll
    for (int s = 1; s <= 10; ++s) {
      acc |= (x << s) | (L >> (64 - s));
      acc |= (x >> s) | (R << (64 - s));
    }
    hds[w] = acc;
  }
  __syncthreads();

  // vertical dilation radius 10 + write packed fg & dil for rows [r0, r0+64)
  for (int w = tid; w < 256; w += 1024) {
    int r = w >> 2, wc = w & 3;
    int gr = r0 + r;
    uint64_t acc = 0ull;
    #pragma unroll
    for (int dr = 0; dr <= 20; ++dr) acc |= hds[(r + dr) * 4 + wc];
    fgw[img * 1024 + gr * 4 + wc]  = fgs[(r + 10) * 4 + wc];
    dilw[img * 1024 + gr * 4 + wc] = acc;
  }
}

// ---------------- kernel B: group + per-pixel hash + histogram --------------
// Each pixel belongs to exactly one group -> hash ONCE with that group's key.
// mgrp[p] = (m << 2) | grp, m = 23-bit uniform mantissa bits.
__global__ __launch_bounds__(256) void hash_hist(const uint64_t* __restrict__ fgw,
                                                 const uint64_t* __restrict__ dilw,
                                                 const uint32_t* __restrict__ keys,
                                                 uint32_t* __restrict__ mgrp,
                                                 uint32_t* __restrict__ hist) {
  __shared__ uint32_t lh[768];
  __shared__ uint64_t fgl[32], dll[32];
  const int tid = threadIdx.x;
  for (int t = tid; t < 768; t += 256) lh[t] = 0;
  const int b = blockIdx.x >> 5;              // 32 blocks per image
  const int base = blockIdx.x * 2048;
  const int w0 = (blockIdx.x & 31) * 32;      // word base within image
  if (tid < 32) fgl[tid] = fgw[b * 1024 + w0 + tid];
  else if (tid < 64) dll[tid - 32] = dilw[b * 1024 + w0 + tid - 32];
  const uint32_t K00 = keys[b * 6 + 0], K01 = keys[b * 6 + 1];
  const uint32_t K10 = keys[b * 6 + 2], K11 = keys[b * 6 + 3];
  const uint32_t K20 = keys[b * 6 + 4], K21 = keys[b * 6 + 5];
  __syncthreads();

  #pragma unroll
  for (int k = 0; k < 8; ++k) {
    int off = k * 256 + tid;                  // 0..2047 within block
    int pix = (base + off) & 65535;
    int lw = off >> 6, bp = off & 63;
    uint32_t fgbit = (uint32_t)((fgl[lw] >> bp) & 1ull);
    uint32_t dilbit = (uint32_t)((dll[lw] >> bp) & 1ull);
    uint32_t grp = fgbit ? 0u : (dilbit ? 1u : 2u);
    uint32_t k0 = grp == 0 ? K00 : grp == 1 ? K10 : K20;
    uint32_t k1 = grp == 0 ? K01 : grp == 1 ? K11 : K21;
    uint32_t x0 = 0u, x1 = (uint32_t)pix;
    tf2x32(k0, k1, x0, x1);
    uint32_t m = (x0 ^ x1) >> 9;
    mgrp[base + off] = (m << 2) | grp;
    atomicAdd(&lh[grp * 256 + (m >> 15)], 1u);
  }
  __syncthreads();
  for (int t = tid; t < 768; t += 256)
    if (lh[t]) atomicAdd(&hist[b * 768 + t], lh[t]);
}

// ---------------- kernel C: thresholds (inline) + emit ----------------------
__global__ __launch_bounds__(256) void topk_emit(const uint32_t* __restrict__ mgrp,
                                                 const uint32_t* __restrict__ hist,
                                                 uint32_t* __restrict__ TG,
                                                 uint32_t* __restrict__ cnt,
                                                 uint32_t* __restrict__ candcnt,
                                                 unsigned long long* __restrict__ cand,
                                                 int* __restrict__ idx_out) {
  __shared__ uint32_t hh[768];
  __shared__ uint32_t sT[3], loc[3], lbd[3], basA[3], basB[3];
  const int tid = threadIdx.x;
  const int b = blockIdx.x >> 5;
  const int base = blockIdx.x * 2048;
  for (int t = tid; t < 768; t += 256) hh[t] = hist[b * 768 + t];
  if (tid < 3) { loc[tid] = 0; lbd[tid] = 0; }
  __syncthreads();

  if (tid < 3) {
    uint32_t nsel = tid == 0 ? NFG : tid == 1 ? NRING : NBG;
    const uint32_t* h = hh + tid * 256;
    uint32_t cum = 0; int T = 255;
    for (; T > 0; --T) {
      uint32_t c = h[T];
      if (cum + c >= nsel) break;
      cum += c;
    }
    sT[tid] = (uint32_t)T;
    if ((blockIdx.x & 31) == 0) {
      TG[(b * 3 + tid) * 2] = (uint32_t)T;
      TG[(b * 3 + tid) * 2 + 1] = cum;      // count strictly above bucket T
    }
  }
  __syncthreads();
  const uint32_t T0 = sT[0], T1 = sT[1], T2 = sT[2];

  #pragma unroll
  for (int k = 0; k < 8; ++k) {
    uint32_t v = mgrp[base + k * 256 + tid];
    uint32_t g = v & 3u, bin = v >> 17;
    uint32_t T = g == 0 ? T0 : g == 1 ? T1 : T2;
    if (bin > T) atomicAdd(&loc[g], 1u);
    else if (bin == T) atomicAdd(&lbd[g], 1u);
  }
  __syncthreads();
  if (tid < 3) {
    basA[tid] = atomicAdd(&cnt[b * 3 + tid], loc[tid]);
    basB[tid] = atomicAdd(&candcnt[b * 3 + tid], lbd[tid]);
    loc[tid] = 0; lbd[tid] = 0;
  }
  __syncthreads();

  #pragma unroll
  for (int k = 0; k < 8; ++k) {
    int p = base + k * 256 + tid;
    uint32_t v = mgrp[p];
    uint32_t g = v & 3u, bin = v >> 17;
    uint32_t T = g == 0 ? T0 : g == 1 ? T1 : T2;
    int pix = p & 65535;
    if (bin > T) {
      uint32_t o = atomicAdd(&loc[g], 1u);
      int seg = g == 0 ? 0 : g == 1 ? NFG : (NFG + NRING);
      idx_out[b * KSEL + seg + (int)(basA[g] + o)] = pix;
    } else if (bin == T) {
      uint32_t o = atomicAdd(&lbd[g], 1u);
      uint32_t c = basB[g] + o;
      uint32_t m = v >> 2;
      if (c < 1024u)
        cand[(b * 3 + g) * 1024 + c] = ((unsigned long long)m << 16) | (uint32_t)pix;
    }
  }
}

// ---------------- kernel D: gather + fused tie-break rank + transpose -------
// 1024 blocks x 256 thr; 16 anchors/block. Boundary blocks (window reaching
// positions >= G in their segment) recompute the exact rank locally from the
// candidate set (order-independent => bit-identical to jax.lax.top_k).
#define GA 16
__global__ __launch_bounds__(256) void gather_rank_t(
    const float* __restrict__ feats, const int* __restrict__ idx,
    const uint32_t* __restrict__ TG, const uint32_t* __restrict__ candcnt,
    const unsigned long long* __restrict__ cand, float* __restrict__ fsT) {
  __shared__ float tile[GA * 65];
  __shared__ float ssb[16 * GA];
  __shared__ int lidx[GA];
  __shared__ unsigned long long cb[1024];
  const int tid = threadIdx.x;
  const int img = blockIdx.x >> 7;            // 128 blocks per image
  const int win = (blockIdx.x & 127) * GA;    // anchor window within image
  int seg, segoff, nsel;
  if (win < NFG)               { seg = 0; segoff = 0;            nsel = NFG; }
  else if (win < NFG + NRING)  { seg = 1; segoff = NFG;          nsel = NRING; }
  else                         { seg = 2; segoff = NFG + NRING;  nsel = NBG; }
  const int task = img * 3 + seg;
  const uint32_t G = TG[task * 2 + 1];
  const int poslo = win - segoff;

  if (tid < GA) {
    if ((uint32_t)(poslo + tid) < G)
      lidx[tid] = idx[img * KSEL + win + tid];
  }
  const bool needRank = (uint32_t)(poslo + GA) > G;   // block-uniform
  if (needRank) {
    const int c = (int)(candcnt[task] < 1024u ? candcnt[task] : 1024u);
    const int r = nsel - (int)G;
    for (int i = tid; i < c; i += 256) cb[i] = cand[task * 1024 + i];
    __syncthreads();
    for (int i = tid; i < c; i += 256) {
      unsigned long long me = cb[i];
      uint32_t mm = (uint32_t)(me >> 16), pi = (uint32_t)(me & 0xFFFFu);
      int rank = 0;
      for (int j = 0; j < c; ++j) {
        unsigned long long o = cb[j];
        uint32_t om = (uint32_t)(o >> 16), op = (uint32_t)(o & 0xFFFFu);
        if (om > mm || (om == mm && op < pi)) ++rank;
      }
      if (rank < r) {
        int slot = (int)G + rank - poslo;
        if (slot >= 0 && slot < GA) lidx[slot] = (int)pi;
      }
    }
  }
  __syncthreads();

  // gather: a = tid&15 anchor, q = tid>>4 handles channels q*4 .. q*4+3
  const int a = tid & 15, q = tid >> 4;
  const int pix = lidx[a];
  const float* fb = feats + ((size_t)img * NCH + q * 4) * NPIX + pix;
  float ss = 0.f;
  #pragma unroll
  for (int k = 0; k < 4; ++k) {
    float v = fb[(size_t)k * NPIX];
    tile[a * 65 + q * 4 + k] = v;
    ss += v * v;
  }
  ssb[q * GA + a] = ss;
  __syncthreads();
  float tot = 0.f;
  #pragma unroll
  for (int q2 = 0; q2 < 16; ++q2) tot += ssb[q2 * GA + a];
  float scale = 1.0f / fmaxf(sqrtf(tot), 1e-12f);
  float* dst = fsT + (size_t)img * NCH * KSEL + win;
  #pragma unroll
  for (int k = 0; k < 4; ++k) {
    int c = q * 4 + k;
    dst[(size_t)c * KSEL + a] = tile[a * 65 + c] * scale;
  }
}

// ---------------- kernel E: loss GEMM (16 anchors x 2048 cols per block) ----
#define LTA 16
__global__ __launch_bounds__(256) void loss_main(const float* __restrict__ fsT,
                                                 float* __restrict__ out) {
  const int img = blockIdx.x & 7;             // XCD swizzle
  const int a0 = (blockIdx.x >> 3) * LTA;
  const float* F = fsT + (size_t)img * NCH * KSEL;
  const float4* F4 = (const float4*)F;
  const int tid = threadIdx.x;

  __shared__ float As[LTA * 64];
  __shared__ float redD[4][LTA], redP[4][LTA], terms[LTA];
  for (int t = tid; t < LTA * 64; t += 256) {
    int a = t & 15, c = t >> 4;
    As[a * 64 + c] = F[(size_t)c * KSEL + a0 + a];
  }
  __syncthreads();

  float acc[LTA][8];
  #pragma unroll
  for (int a = 0; a < LTA; ++a)
    #pragma unroll
    for (int jj = 0; jj < 8; ++jj) acc[a][jj] = 0.f;

  #pragma unroll 2
  for (int c = 0; c < 64; ++c) {
    float4 b0 = F4[c * 512 + tid];            // j = 4*tid + [0..3]  (fg cols)
    float4 b1 = F4[c * 512 + 256 + tid];      // j = 1024 + 4*tid + [0..3]
    #pragma unroll
    for (int a = 0; a < LTA; ++a) {
      float av = As[a * 64 + c];
      acc[a][0] += av * b0.x; acc[a][1] += av * b0.y;
      acc[a][2] += av * b0.z; acc[a][3] += av * b0.w;
      acc[a][4] += av * b1.x; acc[a][5] += av * b1.y;
      acc[a][6] += av * b1.z; acc[a][7] += av * b1.w;
    }
  }

  float pD[LTA], pP[LTA];
  const int jb = 4 * tid;
  #pragma unroll
  for (int a = 0; a < LTA; ++a) {
    const int ag = a0 + a;
    float p = 0.f, d = 0.f;
    #pragma unroll
    for (int jj = 0; jj < 4; ++jj) {
      float e = __expf(acc[a][jj] * INV_TEMP);
      if (jb + jj == ag) e = 0.f;             // ~eye
      p += e;
    }
    #pragma unroll
    for (int jj = 0; jj < 4; ++jj) d += __expf(acc[a][4 + jj] * INV_TEMP);
    pD[a] = d + p;
    pP[a] = p;
  }

  #pragma unroll
  for (int o = 32; o > 0; o >>= 1) {
    #pragma unroll
    for (int a = 0; a < LTA; ++a) {
      pD[a] += __shfl_xor(pD[a], o);
      pP[a] += __shfl_xor(pP[a], o);
    }
  }
  if ((tid & 63) == 0) {
    #pragma unroll
    for (int a = 0; a < LTA; ++a) {
      redD[tid >> 6][a] = pD[a];
      redP[tid >> 6][a] = pP[a];
    }
  }
  __syncthreads();
  if (tid < LTA) {
    float d = redD[0][tid] + redD[1][tid] + redD[2][tid] + redD[3][tid];
    float p = redP[0][tid] + redP[1][tid] + redP[2][tid] + redP[3][tid];
    d = fmaxf(d, 1e-8f); p = fmaxf(p, 1e-8f);
    terms[tid] = __logf(d) - __logf(p);
  }
  __syncthreads();
  if (tid == 0) {
    float s = 0.f;
    #pragma unroll
    for (int a = 0; a < LTA; ++a) s += terms[a];
    atomicAdd(out, s * (1.0f / (NFG * NIMG)));
  }
}

// ---------------- launcher ---------------------------------------------------
extern "C" void kernel_launch(void* const* d_in, const int* in_sizes, int n_in,
                              void* d_out, int out_size, void* d_ws, size_t ws_size,
                              hipStream_t stream) {
  const float* feats = (const float*)d_in[0];
  const int* labels  = (const int*)d_in[1];
  float* out = (float*)d_out;

  char* ws = (char*)d_ws;
  uint64_t* fgw     = (uint64_t*)(ws);                      // 64 KB [8][1024]
  uint64_t* dilw    = (uint64_t*)(ws + 65536);              // 64 KB
  uint32_t* keys    = (uint32_t*)(ws + 131072);             // 256 B
  uint32_t* TG      = (uint32_t*)(ws + 131328);             // 256 B
  // --- zero region @131584: hist (24576) + cnt (128) + candcnt (128) ------
  uint32_t* hist    = (uint32_t*)(ws + 131584);
  uint32_t* cnt     = (uint32_t*)(ws + 156160);
  uint32_t* candcnt = (uint32_t*)(ws + 156288);             // ends 156416
  // ------------------------------------------------------------------------
  unsigned long long* cand = (unsigned long long*)(ws + 156416); // 192 KB
  int*      idx     = (int*)(ws + 353024);                  // 64 KB
  uint32_t* mgrp    = (uint32_t*)(ws + 524288);             // 2 MB
  float*    fsT     = (float*)(ws + 2621440);               // 4 MB

  hipLaunchKernelGGL(dilate_pack, dim3(32), dim3(1024), 0, stream,
                     labels, fgw, dilw, (float4*)hist, keys, out);
  hipLaunchKernelGGL(hash_hist, dim3(NIMG * 32), dim3(256), 0, stream,
                     fgw, dilw, keys, mgrp, hist);
  hipLaunchKernelGGL(topk_emit, dim3(NIMG * 32), dim3(256), 0, stream,
                     mgrp, hist, TG, cnt, candcnt, cand, idx);
  hipLaunchKernelGGL(gather_rank_t, dim3((NIMG * KSEL) / GA), dim3(256), 0, stream,
                     feats, idx, TG, candcnt, cand, fsT);
  hipLaunchKernelGGL(loss_main, dim3(NIMG * (NFG / LTA)), dim3(256), 0, stream,
                     fsT, out);
}

// Round 6
// 243.907 us; speedup vs baseline: 6.4591x; 1.0265x over previous
//
#include <hip/hip_runtime.h>
#include <stdint.h>

#define NPIX   65536
#define NIMG   8
#define NCH    64
#define KSEL   2048
#define NFG    1024
#define NRING  768
#define NBG    256
#define INV_TEMP 14.285714285714286f   // 1/0.07

typedef __attribute__((ext_vector_type(8))) short bf16x8;
typedef __attribute__((ext_vector_type(4))) float f32x4;

// ---------------- Threefry-2x32 (20 rounds), exactly as JAX's lowering ------
__device__ __forceinline__ void tf2x32(uint32_t k0, uint32_t k1,
                                       uint32_t& x0, uint32_t& x1) {
  const uint32_t ks2 = k0 ^ k1 ^ 0x1BD11BDAu;
  x0 += k0; x1 += k1;
#define TF_RND(r) { x0 += x1; x1 = (x1 << (r)) | (x1 >> (32 - (r))); x1 ^= x0; }
  TF_RND(13) TF_RND(15) TF_RND(26) TF_RND(6)
  x0 += k1;  x1 += ks2 + 1u;
  TF_RND(17) TF_RND(29) TF_RND(16) TF_RND(24)
  x0 += ks2; x1 += k0 + 2u;
  TF_RND(13) TF_RND(15) TF_RND(26) TF_RND(6)
  x0 += k0;  x1 += k1 + 3u;
  TF_RND(17) TF_RND(29) TF_RND(16) TF_RND(24)
  x0 += k1;  x1 += ks2 + 4u;
  TF_RND(13) TF_RND(15) TF_RND(26) TF_RND(6)
  x0 += ks2; x1 += k0 + 5u;
#undef TF_RND
}

// float -> bf16 round-to-nearest-even
__device__ __forceinline__ ushort f2bf(float f) {
  uint32_t u = __float_as_uint(f);
  return (ushort)((u + 0x7FFFu + ((u >> 16) & 1u)) >> 16);
}

// ---------------- kernel A: bit-packed separable dilation + side duties -----
// 32 blocks = 8 images x 4 row-bands of 64 rows (+10 halo each side).
#define ZERO_F4 1552
__global__ __launch_bounds__(1024) void dilate_pack(const int* __restrict__ labels,
                                                    uint64_t* __restrict__ fgw,
                                                    uint64_t* __restrict__ dilw,
                                                    float4* __restrict__ zregion,
                                                    uint32_t* __restrict__ keys,
                                                    float* __restrict__ out) {
  __shared__ uint64_t fgs[336], hds[336];   // 84 rows x 4 words
  const int tid = threadIdx.x;
  const int img = blockIdx.x >> 2;
  const int r0 = (blockIdx.x & 3) * 64;

  if (blockIdx.x == 0) {
    for (int t = tid; t < ZERO_F4; t += 1024)
      zregion[t] = make_float4(0.f, 0.f, 0.f, 0.f);
  } else if (blockIdx.x == 1 && tid == 0) {
    out[0] = 0.0f;
    for (int b = 0; b < NIMG; ++b) {
      uint32_t kb0 = 0u, kb1 = (uint32_t)b;
      tf2x32(0u, 1u, kb0, kb1);   // JAX partitionable split: key(1) fold b
      for (int g = 0; g < 3; ++g) {
        uint32_t x0 = 0u, x1 = (uint32_t)g;
        tf2x32(kb0, kb1, x0, x1);
        keys[(b * 3 + g) * 2 + 0] = x0;
        keys[(b * 3 + g) * 2 + 1] = x1;
      }
    }
  }

  // pack fg bits for rows [r0-10, r0+74) (clamped rows contribute 0)
  #pragma unroll
  for (int it = 0; it < 21; ++it) {
    int li = it * 1024 + tid;                // 0 .. 21503 (84*256)
    int hr = r0 - 10 + (li >> 8);
    int col = li & 255;
    bool bit = false;
    if (hr >= 0 && hr < 256) bit = (labels[(img << 16) + (hr << 8) + col] == 1);
    uint64_t m = __ballot(bit);
    if ((tid & 63) == 0) fgs[li >> 6] = m;
  }
  __syncthreads();

  // horizontal dilation radius 10 within each row (4 words/row)
  for (int w = tid; w < 336; w += 1024) {
    int wc = w & 3;
    uint64_t x = fgs[w];
    uint64_t L = wc > 0 ? fgs[w - 1] : 0ull;
    uint64_t R = wc < 3 ? fgs[w + 1] : 0ull;
    uint64_t acc = x;
    #pragma unroll
    for (int s = 1; s <= 10; ++s) {
      acc |= (x << s) | (L >> (64 - s));
      acc |= (x >> s) | (R << (64 - s));
    }
    hds[w] = acc;
  }
  __syncthreads();

  // vertical dilation radius 10 + write packed fg & dil for rows [r0, r0+64)
  for (int w = tid; w < 256; w += 1024) {
    int r = w >> 2, wc = w & 3;
    int gr = r0 + r;
    uint64_t acc = 0ull;
    #pragma unroll
    for (int dr = 0; dr <= 20; ++dr) acc |= hds[(r + dr) * 4 + wc];
    fgw[img * 1024 + gr * 4 + wc]  = fgs[(r + 10) * 4 + wc];
    dilw[img * 1024 + gr * 4 + wc] = acc;
  }
}

// ---------------- kernel B: group + per-pixel hash + histogram --------------
__global__ __launch_bounds__(256) void hash_hist(const uint64_t* __restrict__ fgw,
                                                 const uint64_t* __restrict__ dilw,
                                                 const uint32_t* __restrict__ keys,
                                                 uint32_t* __restrict__ mgrp,
                                                 uint32_t* __restrict__ hist) {
  __shared__ uint32_t lh[768];
  __shared__ uint64_t fgl[32], dll[32];
  const int tid = threadIdx.x;
  for (int t = tid; t < 768; t += 256) lh[t] = 0;
  const int b = blockIdx.x >> 5;              // 32 blocks per image
  const int base = blockIdx.x * 2048;
  const int w0 = (blockIdx.x & 31) * 32;      // word base within image
  if (tid < 32) fgl[tid] = fgw[b * 1024 + w0 + tid];
  else if (tid < 64) dll[tid - 32] = dilw[b * 1024 + w0 + tid - 32];
  const uint32_t K00 = keys[b * 6 + 0], K01 = keys[b * 6 + 1];
  const uint32_t K10 = keys[b * 6 + 2], K11 = keys[b * 6 + 3];
  const uint32_t K20 = keys[b * 6 + 4], K21 = keys[b * 6 + 5];
  __syncthreads();

  #pragma unroll
  for (int k = 0; k < 8; ++k) {
    int off = k * 256 + tid;                  // 0..2047 within block
    int pix = (base + off) & 65535;
    int lw = off >> 6, bp = off & 63;
    uint32_t fgbit = (uint32_t)((fgl[lw] >> bp) & 1ull);
    uint32_t dilbit = (uint32_t)((dll[lw] >> bp) & 1ull);
    uint32_t grp = fgbit ? 0u : (dilbit ? 1u : 2u);
    uint32_t k0 = grp == 0 ? K00 : grp == 1 ? K10 : K20;
    uint32_t k1 = grp == 0 ? K01 : grp == 1 ? K11 : K21;
    uint32_t x0 = 0u, x1 = (uint32_t)pix;
    tf2x32(k0, k1, x0, x1);
    uint32_t m = (x0 ^ x1) >> 9;
    mgrp[base + off] = (m << 2) | grp;
    atomicAdd(&lh[grp * 256 + (m >> 15)], 1u);
  }
  __syncthreads();
  for (int t = tid; t < 768; t += 256)
    if (lh[t]) atomicAdd(&hist[b * 768 + t], lh[t]);
}

// ---------------- kernel C: thresholds (inline) + emit ----------------------
__global__ __launch_bounds__(256) void topk_emit(const uint32_t* __restrict__ mgrp,
                                                 const uint32_t* __restrict__ hist,
                                                 uint32_t* __restrict__ TG,
                                                 uint32_t* __restrict__ cnt,
                                                 uint32_t* __restrict__ candcnt,
                                                 unsigned long long* __restrict__ cand,
                                                 int* __restrict__ idx_out) {
  __shared__ uint32_t hh[768];
  __shared__ uint32_t sT[3], loc[3], lbd[3], basA[3], basB[3];
  const int tid = threadIdx.x;
  const int b = blockIdx.x >> 5;
  const int base = blockIdx.x * 2048;
  for (int t = tid; t < 768; t += 256) hh[t] = hist[b * 768 + t];
  if (tid < 3) { loc[tid] = 0; lbd[tid] = 0; }
  __syncthreads();

  if (tid < 3) {
    uint32_t nsel = tid == 0 ? NFG : tid == 1 ? NRING : NBG;
    const uint32_t* h = hh + tid * 256;
    uint32_t cum = 0; int T = 255;
    for (; T > 0; --T) {
      uint32_t c = h[T];
      if (cum + c >= nsel) break;
      cum += c;
    }
    sT[tid] = (uint32_t)T;
    if ((blockIdx.x & 31) == 0) {
      TG[(b * 3 + tid) * 2] = (uint32_t)T;
      TG[(b * 3 + tid) * 2 + 1] = cum;      // count strictly above bucket T
    }
  }
  __syncthreads();
  const uint32_t T0 = sT[0], T1 = sT[1], T2 = sT[2];

  #pragma unroll
  for (int k = 0; k < 8; ++k) {
    uint32_t v = mgrp[base + k * 256 + tid];
    uint32_t g = v & 3u, bin = v >> 17;
    uint32_t T = g == 0 ? T0 : g == 1 ? T1 : T2;
    if (bin > T) atomicAdd(&loc[g], 1u);
    else if (bin == T) atomicAdd(&lbd[g], 1u);
  }
  __syncthreads();
  if (tid < 3) {
    basA[tid] = atomicAdd(&cnt[b * 3 + tid], loc[tid]);
    basB[tid] = atomicAdd(&candcnt[b * 3 + tid], lbd[tid]);
    loc[tid] = 0; lbd[tid] = 0;
  }
  __syncthreads();

  #pragma unroll
  for (int k = 0; k < 8; ++k) {
    int p = base + k * 256 + tid;
    uint32_t v = mgrp[p];
    uint32_t g = v & 3u, bin = v >> 17;
    uint32_t T = g == 0 ? T0 : g == 1 ? T1 : T2;
    int pix = p & 65535;
    if (bin > T) {
      uint32_t o = atomicAdd(&loc[g], 1u);
      int seg = g == 0 ? 0 : g == 1 ? NFG : (NFG + NRING);
      idx_out[b * KSEL + seg + (int)(basA[g] + o)] = pix;
    } else if (bin == T) {
      uint32_t o = atomicAdd(&lbd[g], 1u);
      uint32_t c = basB[g] + o;
      uint32_t m = v >> 2;
      if (c < 1024u)
        cand[(b * 3 + g) * 1024 + c] = ((unsigned long long)m << 16) | (uint32_t)pix;
    }
  }
}

// ---------------- kernel D: gather + fused tie-break rank -> bf16 rows ------
// Output fs[img][j][64] row-major bf16 == MFMA A/B fragment-friendly layout.
#define GA 16
__global__ __launch_bounds__(256) void gather_rank_t(
    const float* __restrict__ feats, const int* __restrict__ idx,
    const uint32_t* __restrict__ TG, const uint32_t* __restrict__ candcnt,
    const unsigned long long* __restrict__ cand, ushort* __restrict__ fs) {
  __shared__ float tile[GA * 65];
  __shared__ float ssb[16 * GA];
  __shared__ float sscale[GA];
  __shared__ int lidx[GA];
  __shared__ unsigned long long cb[1024];
  const int tid = threadIdx.x;
  const int img = blockIdx.x >> 7;            // 128 blocks per image
  const int win = (blockIdx.x & 127) * GA;    // anchor window within image
  int seg, segoff, nsel;
  if (win < NFG)               { seg = 0; segoff = 0;            nsel = NFG; }
  else if (win < NFG + NRING)  { seg = 1; segoff = NFG;          nsel = NRING; }
  else                         { seg = 2; segoff = NFG + NRING;  nsel = NBG; }
  const int task = img * 3 + seg;
  const uint32_t G = TG[task * 2 + 1];
  const int poslo = win - segoff;

  if (tid < GA) {
    if ((uint32_t)(poslo + tid) < G)
      lidx[tid] = idx[img * KSEL + win + tid];
  }
  const bool needRank = (uint32_t)(poslo + GA) > G;   // block-uniform
  if (needRank) {
    const int c = (int)(candcnt[task] < 1024u ? candcnt[task] : 1024u);
    const int r = nsel - (int)G;
    for (int i = tid; i < c; i += 256) cb[i] = cand[task * 1024 + i];
    __syncthreads();
    for (int i = tid; i < c; i += 256) {
      unsigned long long me = cb[i];
      uint32_t mm = (uint32_t)(me >> 16), pi = (uint32_t)(me & 0xFFFFu);
      int rank = 0;
      for (int j = 0; j < c; ++j) {
        unsigned long long o = cb[j];
        uint32_t om = (uint32_t)(o >> 16), op = (uint32_t)(o & 0xFFFFu);
        if (om > mm || (om == mm && op < pi)) ++rank;
      }
      if (rank < r) {
        int slot = (int)G + rank - poslo;
        if (slot >= 0 && slot < GA) lidx[slot] = (int)pi;
      }
    }
  }
  __syncthreads();

  // gather: a = tid&15 anchor, q = tid>>4 handles channels q*4 .. q*4+3
  const int a = tid & 15, q = tid >> 4;
  const int pix = lidx[a];
  const float* fb = feats + ((size_t)img * NCH + q * 4) * NPIX + pix;
  float ss = 0.f;
  #pragma unroll
  for (int k = 0; k < 4; ++k) {
    float v = fb[(size_t)k * NPIX];
    tile[a * 65 + q * 4 + k] = v;
    ss += v * v;
  }
  ssb[q * GA + a] = ss;
  __syncthreads();
  if (q == 0) {
    float tot = 0.f;
    #pragma unroll
    for (int q2 = 0; q2 < 16; ++q2) tot += ssb[q2 * GA + a];
    sscale[a] = 1.0f / fmaxf(sqrtf(tot), 1e-12f);
  }
  __syncthreads();

  // write phase: thread (row = tid>>4, chunk = tid&15) -> contiguous ushort4
  const int row = tid >> 4, c4 = tid & 15;
  const float sc = sscale[row];
  ushort4 v4;
  v4.x = f2bf(tile[row * 65 + c4 * 4 + 0] * sc);
  v4.y = f2bf(tile[row * 65 + c4 * 4 + 1] * sc);
  v4.z = f2bf(tile[row * 65 + c4 * 4 + 2] * sc);
  v4.w = f2bf(tile[row * 65 + c4 * 4 + 3] * sc);
  ((ushort4*)(fs + ((size_t)img * KSEL + win + row) * NCH))[c4] = v4;
}

// ---------------- kernel E: MFMA loss -------------------------------------
// 256 blocks = 8 images x 32 anchor-tiles (32 fg anchors each). 4 waves:
// wave = (row-tile rt in 0..1, col-half colh in 0..1). Each wave: 64 col
// tiles x 2 mfma_f32_16x16x32_bf16 (K=64). Epilogue: exp in D-layout regs
// (col=lane&15, row=quad*4+reg), diagonal mask, lane-shuffle + LDS reduce,
// log(d)-log(p), one atomicAdd per block.
__global__ __launch_bounds__(256) void loss_mfma(const ushort* __restrict__ fs,
                                                 float* __restrict__ out) {
  const int img = blockIdx.x & 7;             // XCD swizzle
  const int a0 = (blockIdx.x >> 3) * 32;
  const ushort* X = fs + (size_t)img * KSEL * NCH;
  const int tid = threadIdx.x;
  const int lane = tid & 63, wave = tid >> 6;
  const int quad = lane >> 4, col = lane & 15;
  const int rt = wave >> 1, colh = wave & 1;

  __shared__ float redD[2][2][16];
  __shared__ float redP[2][16];

  // A fragment: m = lane&15, k = quad*8 + [0..7]; two K-halves of 32
  const int arow = a0 + rt * 16 + col;
  const bf16x8* Ap = (const bf16x8*)(X + (size_t)arow * NCH + quad * 8);
  const bf16x8 a_lo = Ap[0];
  const bf16x8 a_hi = Ap[4];                  // +32 channels = +64 B

  float pD[4] = {0.f, 0.f, 0.f, 0.f};
  float pP[4] = {0.f, 0.f, 0.f, 0.f};
  const int ct0 = colh * 64;
  const int mbase = a0 + rt * 16 + quad * 4;  // D rows for this lane

  for (int ct = ct0; ct < ct0 + 64; ++ct) {
    const int j = ct * 16 + col;              // D column for this lane
    const bf16x8* Bp = (const bf16x8*)(X + (size_t)j * NCH + quad * 8);
    bf16x8 b_lo = Bp[0];
    bf16x8 b_hi = Bp[4];
    f32x4 d = {0.f, 0.f, 0.f, 0.f};
    d = __builtin_amdgcn_mfma_f32_16x16x32_bf16(a_lo, b_lo, d, 0, 0, 0);
    d = __builtin_amdgcn_mfma_f32_16x16x32_bf16(a_hi, b_hi, d, 0, 0, 0);
    #pragma unroll
    for (int r = 0; r < 4; ++r) {
      float e = __expf(d[r] * INV_TEMP);
      if (j == mbase + r) e = 0.f;            // ~eye (only hits in colh 0)
      pD[r] += e;
      if (colh == 0) pP[r] += e;              // fg columns = tiles 0..63
    }
  }

  // reduce across the 16 columns held by this quad's lanes
  #pragma unroll
  for (int o = 1; o < 16; o <<= 1) {
    #pragma unroll
    for (int r = 0; r < 4; ++r) {
      pD[r] += __shfl_xor(pD[r], o);
      pP[r] += __shfl_xor(pP[r], o);
    }
  }
  if (col == 0) {
    #pragma unroll
    for (int r = 0; r < 4; ++r) {
      redD[rt][colh][quad * 4 + r] = pD[r];
      if (colh == 0) redP[rt][quad * 4 + r] = pP[r];
    }
  }
  __syncthreads();

  float term = 0.f;
  if (tid < 32) {
    int lrt = tid >> 4, lr = tid & 15;
    float dsum = fmaxf(redD[lrt][0][lr] + redD[lrt][1][lr], 1e-8f);
    float psum = fmaxf(redP[lrt][lr], 1e-8f);
    term = __logf(dsum) - __logf(psum);
  }
  if (tid < 64) {
    #pragma unroll
    for (int o = 32; o > 0; o >>= 1) term += __shfl_xor(term, o);
    if (tid == 0) atomicAdd(out, term * (1.0f / (NFG * NIMG)));
  }
}

// ---------------- launcher ---------------------------------------------------
extern "C" void kernel_launch(void* const* d_in, const int* in_sizes, int n_in,
                              void* d_out, int out_size, void* d_ws, size_t ws_size,
                              hipStream_t stream) {
  const float* feats = (const float*)d_in[0];
  const int* labels  = (const int*)d_in[1];
  float* out = (float*)d_out;

  char* ws = (char*)d_ws;
  uint64_t* fgw     = (uint64_t*)(ws);                      // 64 KB [8][1024]
  uint64_t* dilw    = (uint64_t*)(ws + 65536);              // 64 KB
  uint32_t* keys    = (uint32_t*)(ws + 131072);             // 256 B
  uint32_t* TG      = (uint32_t*)(ws + 131328);             // 256 B
  // --- zero region @131584: hist (24576) + cnt (128) + candcnt (128) ------
  uint32_t* hist    = (uint32_t*)(ws + 131584);
  uint32_t* cnt     = (uint32_t*)(ws + 156160);
  uint32_t* candcnt = (uint32_t*)(ws + 156288);             // ends 156416
  // ------------------------------------------------------------------------
  unsigned long long* cand = (unsigned long long*)(ws + 156416); // 192 KB
  int*      idx     = (int*)(ws + 353024);                  // 64 KB
  uint32_t* mgrp    = (uint32_t*)(ws + 524288);             // 2 MB
  ushort*   fs      = (ushort*)(ws + 2621440);              // 2 MB bf16 [8][2048][64]

  hipLaunchKernelGGL(dilate_pack, dim3(32), dim3(1024), 0, stream,
                     labels, fgw, dilw, (float4*)hist, keys, out);
  hipLaunchKernelGGL(hash_hist, dim3(NIMG * 32), dim3(256), 0, stream,
                     fgw, dilw, keys, mgrp, hist);
  hipLaunchKernelGGL(topk_emit, dim3(NIMG * 32), dim3(256), 0, stream,
                     mgrp, hist, TG, cnt, candcnt, cand, idx);
  hipLaunchKernelGGL(gather_rank_t, dim3((NIMG * KSEL) / GA), dim3(256), 0, stream,
                     feats, idx, TG, candcnt, cand, fs);
  hipLaunchKernelGGL(loss_mfma, dim3(NIMG * (NFG / 32)), dim3(256), 0, stream,
                     fs, out);
}